// Round 12
// baseline (331.184 us; speedup 1.0000x reference)
//
#include <hip/hip_runtime.h>
#include <hip/hip_bf16.h>

typedef __attribute__((ext_vector_type(8))) short short8;
typedef __attribute__((ext_vector_type(4))) float floatx4;

constexpr int N_ = 4096;
constexpr float SQRT_E = 16.0f;
// q scale folded with log2(e): softmax computed in exp2 domain
constexpr float QSCALE = 0.17677669529663687f * 1.4426950408889634f;

__device__ __forceinline__ ushort f2bf(float x) {
  __hip_bfloat16 h = __float2bfloat16(x);
  return *reinterpret_cast<ushort*>(&h);
}
__device__ __forceinline__ float bf2f(ushort b) {
  unsigned int u = ((unsigned int)b) << 16;
  return __uint_as_float(u);
}

// all 16 lanes of each aligned 16-lane group get the group max (VALU DPP, not LDS)
__device__ __forceinline__ float dpp_max16(float x) {
  int v = __float_as_int(x);
  int y;
  y = __builtin_amdgcn_update_dpp(v, v, 0x128, 0xf, 0xf, false); // row_ror:8
  v = __float_as_int(fmaxf(__int_as_float(v), __int_as_float(y)));
  y = __builtin_amdgcn_update_dpp(v, v, 0x124, 0xf, 0xf, false); // row_ror:4
  v = __float_as_int(fmaxf(__int_as_float(v), __int_as_float(y)));
  y = __builtin_amdgcn_update_dpp(v, v, 0x122, 0xf, 0xf, false); // row_ror:2
  v = __float_as_int(fmaxf(__int_as_float(v), __int_as_float(y)));
  y = __builtin_amdgcn_update_dpp(v, v, 0x121, 0xf, 0xf, false); // row_ror:1
  v = __float_as_int(fmaxf(__int_as_float(v), __int_as_float(y)));
  return __int_as_float(v);
}

// ---------------- transpose helper (device side of mega-prep) ----------------
__device__ __forceinline__ void do_transpose(
    const float* __restrict__ src, ushort* __restrict__ dsth,
    ushort* __restrict__ dstl, int R, int C, int lb, int cb_shift,
    float* smem, int hasLo)
{
  float (*tile)[33] = (float(*)[33])smem;
  const int r0 = (lb >> cb_shift) * 32;
  const int c0 = (lb & ((1 << cb_shift) - 1)) * 32;
  const int tx = threadIdx.x & 31, ty = threadIdx.x >> 5;
  #pragma unroll
  for (int p = 0; p < 4; ++p) {
    const int lr = p*8 + ty;
    tile[lr][tx] = (r0+lr < R && c0+tx < C) ? src[(size_t)(r0+lr)*C + c0 + tx] : 0.f;
  }
  __syncthreads();
  #pragma unroll
  for (int p = 0; p < 4; ++p) {
    const int dc = p*8 + ty;
    if (c0+dc < C && r0+tx < R) {
      const float v = tile[tx][dc];
      const ushort hi = f2bf(v);
      dsth[(size_t)(c0+dc)*R + r0 + tx] = hi;
      if (hasLo) dstl[(size_t)(c0+dc)*R + r0 + tx] = f2bf(v - bf2f(hi));
    }
  }
}

// ---------------- mega-prep: all transposes + hsplit + vinit + k1 in ONE launch --
__global__ __launch_bounds__(256) void k_prep(
    const float* __restrict__ equ, const float* __restrict__ h,
    const float* __restrict__ W_equ, const float* __restrict__ W_gproj,
    const float* __restrict__ W_g1, const float* __restrict__ W_g2,
    const float* __restrict__ W_q, const float* __restrict__ W_k,
    const float* __restrict__ W_v, const float* __restrict__ W_vg,
    const float* __restrict__ W_ng, const float* __restrict__ W_gout,
    const float* __restrict__ W_hdec, const float* __restrict__ W_gdec,
    ushort* __restrict__ Wg1t, ushort* __restrict__ Wg2t,
    ushort* __restrict__ Wth, ushort* __restrict__ Wtl,
    ushort* __restrict__ Wvgt, ushort* __restrict__ Wngt,
    ushort* __restrict__ Wgoutt, ushort* __restrict__ Whdect,
    ushort* __restrict__ Wgdect,
    ushort* __restrict__ h2h, ushort* __restrict__ h2l,
    ushort* __restrict__ vt,
    ushort* __restrict__ g_src_b, ushort* __restrict__ gram_b)
{
  __shared__ __align__(16) float smem[1120];
  const int b = blockIdx.x;
  const int t = threadIdx.x;

  if (b < 512) {            // W_g1 [1024,512] -> Wg1t
    do_transpose(W_g1, Wg1t, nullptr, 1024, 512, b, 4, smem, 0);
  } else if (b < 640) {     // W_g2 [512,256]
    do_transpose(W_g2, Wg2t, nullptr, 512, 256, b-512, 3, smem, 0);
  } else if (b < 768) {     // W_q hi/lo
    do_transpose(W_q, Wth, Wtl, 512, 256, b-640, 3, smem, 1);
  } else if (b < 896) {     // W_k hi/lo
    do_transpose(W_k, Wth + 256*512, Wtl + 256*512, 512, 256, b-768, 3, smem, 1);
  } else if (b < 1024) {    // W_v hi/lo
    do_transpose(W_v, Wth + 512*512, Wtl + 512*512, 512, 256, b-896, 3, smem, 1);
  } else if (b < 1088) {    // W_vg
    do_transpose(W_vg, Wvgt, nullptr, 256, 256, b-1024, 3, smem, 0);
  } else if (b < 1152) {    // W_ng
    do_transpose(W_ng, Wngt, nullptr, 256, 256, b-1088, 3, smem, 0);
  } else if (b < 1216) {    // W_gout
    do_transpose(W_gout, Wgoutt, nullptr, 256, 256, b-1152, 3, smem, 0);
  } else if (b < 1280) {    // W_hdec
    do_transpose(W_hdec, Whdect, nullptr, 256, 256, b-1216, 3, smem, 0);
  } else if (b < 1288) {    // W_gdec [256,16]
    do_transpose(W_gdec, Wgdect, nullptr, 256, 16, b-1280, 0, smem, 0);
  } else if (b < 5384) {    // hsplit: h_src half of h2 (hi/lo)
    const int i = b - 1288;
    const float v = h[(size_t)i*256 + t] * SQRT_E;
    const ushort hi = f2bf(v);
    h2h[(size_t)i*512 + 256 + t] = hi;
    h2l[(size_t)i*512 + 256 + t] = f2bf(v - bf2f(hi));
  } else if (b < 7432) {    // vinit: ones-col + zero ext
    const int idx = (b - 5384)*256 + t;
    const int n = idx & 4095;
    const int c16 = (idx >> 12) & 15;
    const int hh = idx >> 16;
    vt[((size_t)hh*144 + 128 + c16)*N_ + n] = (c16 == 0) ? (ushort)0x3F80 : (ushort)0;
  } else {                  // k1: g_src_b + gram_b
    float* eq   = smem;        // 48
    float* gs   = smem + 48;   // 768
    float* g2p  = smem + 816;  // 96
    float* part = smem + 912;  // 192
    const int i = b - 7432;
    if (t < 48) eq[t] = equ[(size_t)i*48 + t];
    __syncthreads();
    #pragma unroll
    for (int j = 0; j < 3; ++j) {
      float s = 0.f;
      #pragma unroll
      for (int m = 0; m < 16; ++m) s += eq[j*16+m] * W_equ[m*256 + t];
      s *= SQRT_E;
      gs[j*256 + t] = s;
      g_src_b[((size_t)i*3 + j)*256 + t] = f2bf(s);
    }
    __syncthreads();
    if (t < 192) {            // 2-way K-split of the gproj GEMV
      const int o = t % 96, half = t / 96;
      const int j = o >> 5, a = o & 31;
      const int e0 = half * 128;
      float s = 0.f;
      for (int e = 0; e < 128; ++e)
        s += gs[j*256 + e0 + e] * W_gproj[(size_t)(e0+e)*32 + a];
      part[t] = s;
    }
    __syncthreads();
    if (t < 96) g2p[t] = part[t] + part[96 + t];
    __syncthreads();
    #pragma unroll
    for (int r = 0; r < 4; ++r) {
      const int idx = r*256 + t;
      const int a = idx >> 5, bb = idx & 31;
      const float s = g2p[a]*g2p[bb] + g2p[32+a]*g2p[32+bb] + g2p[64+a]*g2p[64+bb];
      gram_b[(size_t)i*1024 + idx] = f2bf(s);
    }
  }
}

// ---------------- GEMM cores: BK=64, double-pumped, register prefetch -----------
template<int KTOT>
__device__ __forceinline__ void gemm_core(
    const ushort* __restrict__ A, const ushort* __restrict__ Bt,
    int bM, int bN, floatx4 acc[4], ushort* As, ushort* Bs)
{
  const int t = threadIdx.x;
  const int wave = t >> 6, lane = t & 63, quad = lane >> 4, m = lane & 15;
  #pragma unroll
  for (int ct = 0; ct < 4; ++ct) acc[ct] = {0.f, 0.f, 0.f, 0.f};
  const int ca = t*2, cb = t*2 + 1;
  const int ra = ca >> 3, pa = ca & 7;
  const int rb = cb >> 3, pb = cb & 7;
  const ushort* pA0 = A  + (size_t)(bM+ra)*KTOT + pa*8;
  const ushort* pA1 = A  + (size_t)(bM+rb)*KTOT + pb*8;
  const ushort* pB0 = Bt + (size_t)(bN+ra)*KTOT + pa*8;
  const ushort* pB1 = Bt + (size_t)(bN+rb)*KTOT + pb*8;
  short8 rA0 = *(const short8*)pA0, rA1 = *(const short8*)pA1;
  short8 rB0 = *(const short8*)pB0, rB1 = *(const short8*)pB1;
  for (int k0 = 0; k0 < KTOT; k0 += 64) {
    __syncthreads();
    *(short8*)&As[ra*72 + pa*8] = rA0;
    *(short8*)&As[rb*72 + pb*8] = rA1;
    *(short8*)&Bs[ra*72 + pa*8] = rB0;
    *(short8*)&Bs[rb*72 + pb*8] = rB1;
    if (k0 + 64 < KTOT) {
      pA0 += 64; pA1 += 64; pB0 += 64; pB1 += 64;
      rA0 = *(const short8*)pA0; rA1 = *(const short8*)pA1;
      rB0 = *(const short8*)pB0; rB1 = *(const short8*)pB1;
    }
    __syncthreads();
    #pragma unroll
    for (int ks = 0; ks < 2; ++ks) {
      const short8 af = *(const short8*)&As[(wave*16 + m)*72 + ks*32 + quad*8];
      #pragma unroll
      for (int ct = 0; ct < 4; ++ct) {
        const short8 bf = *(const short8*)&Bs[(ct*16 + m)*72 + ks*32 + quad*8];
        acc[ct] = __builtin_amdgcn_mfma_f32_16x16x32_bf16(af, bf, acc[ct], 0, 0, 0);
      }
    }
  }
}

template<int KTOT>
__device__ __forceinline__ void gemm_core3(
    const ushort* __restrict__ Ah, const ushort* __restrict__ Al,
    const ushort* __restrict__ Bth, const ushort* __restrict__ Btl,
    int bM, int bN, floatx4 acc[4],
    ushort* Ash, ushort* Asl, ushort* Bsh, ushort* Bsl)
{
  const int t = threadIdx.x;
  const int wave = t >> 6, lane = t & 63, quad = lane >> 4, m = lane & 15;
  #pragma unroll
  for (int ct = 0; ct < 4; ++ct) acc[ct] = {0.f, 0.f, 0.f, 0.f};
  const int ca = t*2, cb = t*2 + 1;
  const int ra = ca >> 3, pa = ca & 7;
  const int rb = cb >> 3, pb = cb & 7;
  const ushort* pAh0 = Ah  + (size_t)(bM+ra)*KTOT + pa*8;
  const ushort* pAh1 = Ah  + (size_t)(bM+rb)*KTOT + pb*8;
  const ushort* pAl0 = Al  + (size_t)(bM+ra)*KTOT + pa*8;
  const ushort* pAl1 = Al  + (size_t)(bM+rb)*KTOT + pb*8;
  const ushort* pBh0 = Bth + (size_t)(bN+ra)*KTOT + pa*8;
  const ushort* pBh1 = Bth + (size_t)(bN+rb)*KTOT + pb*8;
  const ushort* pBl0 = Btl + (size_t)(bN+ra)*KTOT + pa*8;
  const ushort* pBl1 = Btl + (size_t)(bN+rb)*KTOT + pb*8;
  short8 rAh0 = *(const short8*)pAh0, rAh1 = *(const short8*)pAh1;
  short8 rAl0 = *(const short8*)pAl0, rAl1 = *(const short8*)pAl1;
  short8 rBh0 = *(const short8*)pBh0, rBh1 = *(const short8*)pBh1;
  short8 rBl0 = *(const short8*)pBl0, rBl1 = *(const short8*)pBl1;
  for (int k0 = 0; k0 < KTOT; k0 += 64) {
    __syncthreads();
    *(short8*)&Ash[ra*72 + pa*8] = rAh0;
    *(short8*)&Ash[rb*72 + pb*8] = rAh1;
    *(short8*)&Asl[ra*72 + pa*8] = rAl0;
    *(short8*)&Asl[rb*72 + pb*8] = rAl1;
    *(short8*)&Bsh[ra*72 + pa*8] = rBh0;
    *(short8*)&Bsh[rb*72 + pb*8] = rBh1;
    *(short8*)&Bsl[ra*72 + pa*8] = rBl0;
    *(short8*)&Bsl[rb*72 + pb*8] = rBl1;
    if (k0 + 64 < KTOT) {
      pAh0 += 64; pAh1 += 64; pAl0 += 64; pAl1 += 64;
      pBh0 += 64; pBh1 += 64; pBl0 += 64; pBl1 += 64;
      rAh0 = *(const short8*)pAh0; rAh1 = *(const short8*)pAh1;
      rAl0 = *(const short8*)pAl0; rAl1 = *(const short8*)pAl1;
      rBh0 = *(const short8*)pBh0; rBh1 = *(const short8*)pBh1;
      rBl0 = *(const short8*)pBl0; rBl1 = *(const short8*)pBl1;
    }
    __syncthreads();
    #pragma unroll
    for (int ks = 0; ks < 2; ++ks) {
      const short8 ah = *(const short8*)&Ash[(wave*16 + m)*72 + ks*32 + quad*8];
      const short8 al = *(const short8*)&Asl[(wave*16 + m)*72 + ks*32 + quad*8];
      #pragma unroll
      for (int ct = 0; ct < 4; ++ct) {
        const short8 bh = *(const short8*)&Bsh[(ct*16 + m)*72 + ks*32 + quad*8];
        const short8 bl = *(const short8*)&Bsl[(ct*16 + m)*72 + ks*32 + quad*8];
        acc[ct] = __builtin_amdgcn_mfma_f32_16x16x32_bf16(ah, bl, acc[ct], 0, 0, 0);
        acc[ct] = __builtin_amdgcn_mfma_f32_16x16x32_bf16(al, bh, acc[ct], 0, 0, 0);
        acc[ct] = __builtin_amdgcn_mfma_f32_16x16x32_bf16(ah, bh, acc[ct], 0, 0, 0);
      }
    }
  }
}

// G1: hidden = relu(gram @ W_g1 + b_g1)
__global__ __launch_bounds__(256) void k_g1(
    const ushort* __restrict__ gram_b, const ushort* __restrict__ Wg1t,
    const float* __restrict__ b_g1, ushort* __restrict__ hidden)
{
  __shared__ __align__(16) ushort As[64*72], Bs[64*72];
  floatx4 acc[4];
  const int bM = blockIdx.x*64, bN = blockIdx.y*64;
  gemm_core<1024>(gram_b, Wg1t, bM, bN, acc, As, Bs);
  const int lane = threadIdx.x & 63, wave = threadIdx.x >> 6;
  const int quad = lane >> 4, m = lane & 15;
  #pragma unroll
  for (int ct = 0; ct < 4; ++ct) {
    const int c = bN + ct*16 + m;
    #pragma unroll
    for (int r = 0; r < 4; ++r) {
      const int i = bM + wave*16 + quad*4 + r;
      hidden[(size_t)i*512 + c] = f2bf(fmaxf(acc[ct][r] + b_g1[c], 0.f));
    }
  }
}

// G2: g2 = hidden @ W_g2 + b_g2 -> hi/lo into h2 cols 0..255
__global__ __launch_bounds__(256) void k_g2(
    const ushort* __restrict__ hidden, const ushort* __restrict__ Wg2t,
    const float* __restrict__ b_g2, ushort* __restrict__ h2h, ushort* __restrict__ h2l)
{
  __shared__ __align__(16) ushort As[64*72], Bs[64*72];
  floatx4 acc[4];
  const int bM = blockIdx.x*64, bN = blockIdx.y*64;
  gemm_core<512>(hidden, Wg2t, bM, bN, acc, As, Bs);
  const int lane = threadIdx.x & 63, wave = threadIdx.x >> 6;
  const int quad = lane >> 4, m = lane & 15;
  #pragma unroll
  for (int ct = 0; ct < 4; ++ct) {
    const int c = bN + ct*16 + m;
    #pragma unroll
    for (int r = 0; r < 4; ++r) {
      const int i = bM + wave*16 + quad*4 + r;
      const float s = acc[ct][r] + b_g2[c];
      const ushort hi = f2bf(s);
      h2h[(size_t)i*512 + c] = hi;
      h2l[(size_t)i*512 + c] = f2bf(s - bf2f(hi));
    }
  }
}

// G3+G4 fused: q/k hi/lo 3-term; v 1-term; vg 1-term
__global__ __launch_bounds__(256) void k_g34(
    const ushort* __restrict__ h2h, const ushort* __restrict__ h2l,
    const ushort* __restrict__ Wth, const ushort* __restrict__ Wtl,
    const float* __restrict__ b_q, const float* __restrict__ b_k,
    const float* __restrict__ b_v,
    const ushort* __restrict__ g_src_b, const ushort* __restrict__ Wvgt,
    float* __restrict__ q_ws, ushort* __restrict__ kh, ushort* __restrict__ kl,
    ushort* __restrict__ vt)
{
  __shared__ __align__(16) ushort S0[64*72], S1[64*72], S2[64*72], S3[64*72];
  const int lb = blockIdx.y*192 + blockIdx.x;     // grid (192,8) = 1536
  const int lane = threadIdx.x & 63, wave = threadIdx.x >> 6;
  const int quad = lane >> 4, m = lane & 15;
  floatx4 acc[4];
  if (lb < 768) {
    const int bM = (lb & 63)*64, bN = (lb >> 6)*64;
    if (bN < 512) {
      gemm_core3<512>(h2h, h2l, Wth, Wtl, bM, bN, acc, S0, S1, S2, S3);
      #pragma unroll
      for (int ct = 0; ct < 4; ++ct) {
        const int c = bN + ct*16 + m;
        #pragma unroll
        for (int r = 0; r < 4; ++r) {
          const int i = bM + wave*16 + quad*4 + r;
          if (c < 256) {
            const float s = acc[ct][r] + b_q[c];
            q_ws[((size_t)(c >> 5)*N_ + i)*32 + (c & 31)] = s * QSCALE;
          } else {
            const int cc = c - 256;
            const float s = acc[ct][r] + b_k[cc];
            const ushort hi = f2bf(s);
            kh[((size_t)(cc >> 5)*N_ + i)*32 + (cc & 31)] = hi;
            kl[((size_t)(cc >> 5)*N_ + i)*32 + (cc & 31)] = f2bf(s - bf2f(hi));
          }
        }
      }
    } else {
      gemm_core<512>(h2h, Wth, bM, bN, acc, S0, S1);
      #pragma unroll
      for (int ct = 0; ct < 4; ++ct) {
        const int cc = bN + ct*16 + m - 512;
        #pragma unroll
        for (int r = 0; r < 4; ++r) {
          const int i = bM + wave*16 + quad*4 + r;
          const float s = acc[ct][r] + b_v[cc];
          vt[((size_t)(cc >> 5)*144 + (cc & 31))*N_ + i] = f2bf(s);
        }
      }
    }
  } else {
    const int lb2 = lb - 768;
    const int bM = (lb2 >> 2)*64, bN = (lb2 & 3)*64;
    gemm_core<256>(g_src_b, Wvgt, bM, bN, acc, S0, S1);
    #pragma unroll
    for (int ct = 0; ct < 4; ++ct) {
      const int c = bN + ct*16 + m;
      const int hh = c >> 5, d = c & 31;
      #pragma unroll
      for (int r = 0; r < 4; ++r) {
        const int i3 = bM + wave*16 + quad*4 + r;
        const int i = i3 / 3, j = i3 - 3*i;
        vt[((size_t)hh*144 + 32 + j*32 + d)*N_ + i] = f2bf(acc[ct][r]);
      }
    }
  }
}

// ---------------- K3: MFMA flash attention v7 -----------------------------------
// TK=32 key-tiles (LDS ~19.5 KB -> 5+ blocks/CU), split-K x3 over 128 tiles,
// register-prefetch, ones-col denominator, deferred rescale, DPP max,
// truncated-bf16 P, exp2-domain softmax.
__global__ __launch_bounds__(256, 5) void k3_attn(
    const float* __restrict__ q_ws, const ushort* __restrict__ kh,
    const ushort* __restrict__ kl, const ushort* __restrict__ vt,
    ushort* __restrict__ Po0, ushort* __restrict__ Po1, ushort* __restrict__ Po2,
    float* __restrict__ Pml)
{
  __shared__ __align__(16) ushort Khs[32*40], Kls[32*40];  // 2.5 KiB each
  __shared__ __align__(16) ushort Vs[144*32];              // 9 KiB swizzled
  __shared__ __align__(16) ushort Pl[4*16*40];             // 5 KiB
  __shared__ float li_s[64];

  const int t    = threadIdx.x;
  const int wave = t >> 6;
  const int lane = t & 63;
  const int quad = lane >> 4;
  const int m    = lane & 15;
  const int h    = blockIdx.y;
  const int s    = blockIdx.z;
  const int n0q  = blockIdx.x * 64;

  const int ktb = (s == 0) ? 0  : (s == 1 ? 43 : 86);
  const int kte = (s == 0) ? 43 : (s == 1 ? 86 : 128);

  // Q fragments: direct global load + hi/lo split in registers
  union { short8 v; ushort u[8]; } Aqh, Aql;
  {
    const float* qp = q_ws + ((size_t)h*N_ + n0q + wave*16 + m)*32 + quad*8;
    #pragma unroll
    for (int jj = 0; jj < 8; ++jj) {
      const float x = qp[jj];
      const ushort hi = f2bf(x);
      Aqh.u[jj] = hi;
      Aql.u[jj] = f2bf(x - bf2f(hi));
    }
  }

  floatx4 Of[9];                     // nt 0..7 = values, nt 8 = denominator col
  #pragma unroll
  for (int nt = 0; nt < 9; ++nt) Of[nt] = {0.f, 0.f, 0.f, 0.f};
  float mi[4];
  #pragma unroll
  for (int r = 0; r < 4; ++r) mi[r] = -3.0e38f;

  // K staging: threads 0..127 stage Khs, 128..255 stage Kls (1 chunk each)
  const int tt = t & 127;
  const int krow = tt >> 2, kch = (tt & 3) * 8;
  const ushort* pK = ((t < 128) ? kh : kl)
                     + ((size_t)h*N_ + ktb*32 + krow)*32 + kch;
  // V staging: chunks t, 256+t, 512+t(t<64); 4 chunks of 8 per 32-key row
  const int vrow0 = t >> 2,        vg0 = t & 3;
  const int vrow1 = (256+t) >> 2,  vg1 = (256+t) & 3;
  const int vrow2 = (512+t) >> 2,  vg2 = (512+t) & 3;   // valid t<64
  const ushort* pV0 = vt + ((size_t)h*144 + vrow0)*N_ + ktb*32 + vg0*8;
  const ushort* pV1 = vt + ((size_t)h*144 + vrow1)*N_ + ktb*32 + vg1*8;
  const ushort* pV2 = vt + ((size_t)h*144 + vrow2)*N_ + ktb*32 + vg2*8;
  const int wV0 = (vrow0*4 + (vg0 ^ (vrow0 & 3)))*8;
  const int wV1 = (vrow1*4 + (vg1 ^ (vrow1 & 3)))*8;
  const int wV2 = (vrow2*4 + (vg2 ^ (vrow2 & 3)))*8;

  // fetch first tile
  short8 rK  = *(const short8*)pK;
  short8 rV0 = *(const short8*)pV0;
  short8 rV1 = *(const short8*)pV1;
  short8 rV2e;
  if (t < 64) rV2e = *(const short8*)pV2;

  for (int kt = ktb; kt < kte; ++kt) {
    __syncthreads();   // prior tile's LDS reads complete
    if (t < 128) *(short8*)&Khs[krow*40 + kch] = rK;
    else         *(short8*)&Kls[krow*40 + kch] = rK;
    *(short8*)&Vs[wV0] = rV0;
    *(short8*)&Vs[wV1] = rV1;
    if (t < 64) *(short8*)&Vs[wV2] = rV2e;
    if (kt + 1 < kte) {
      pK += 1024;
      rK = *(const short8*)pK;
      pV0 += 32; pV1 += 32;
      rV0 = *(const short8*)pV0;
      rV1 = *(const short8*)pV1;
      if (t < 64) { pV2 += 32; rV2e = *(const short8*)pV2; }
    }
    __syncthreads();   // LDS writes visible

    // S = Q K^T (3-term hi/lo MFMA), 32 keys -> 2 kb tiles
    floatx4 sf[2];
    #pragma unroll
    for (int kb = 0; kb < 2; ++kb) {
      const short8 bkh = *(const short8*)&Khs[(kb*16 + m)*40 + quad*8];
      const short8 bkl = *(const short8*)&Kls[(kb*16 + m)*40 + quad*8];
      floatx4 sv = {0.f, 0.f, 0.f, 0.f};
      sv = __builtin_amdgcn_mfma_f32_16x16x32_bf16(Aqh.v, bkl, sv, 0, 0, 0);
      sv = __builtin_amdgcn_mfma_f32_16x16x32_bf16(Aql.v, bkh, sv, 0, 0, 0);
      sv = __builtin_amdgcn_mfma_f32_16x16x32_bf16(Aqh.v, bkh, sv, 0, 0, 0);
      sf[kb] = sv;
    }

    // deferred rescale: only rescale O when tile max exceeds applied max by >20
    float tm[4];
    bool need = false;
    #pragma unroll
    for (int r = 0; r < 4; ++r) {
      float nm = fmaxf(sf[0][r], sf[1][r]);
      tm[r] = dpp_max16(nm);
      need |= (tm[r] > mi[r] + 20.f);
    }
    if (__any(need)) {
      #pragma unroll
      for (int r = 0; r < 4; ++r) {
        const float mn = fmaxf(mi[r], tm[r]);
        const float al = exp2f(mi[r] - mn);
        mi[r] = mn;
        #pragma unroll
        for (int nt = 0; nt < 9; ++nt) Of[nt][r] *= al;
      }
    }
    // P = exp2(S - mi_applied), truncated to bf16 (bounded by 2^20)
    #pragma unroll
    for (int kb = 0; kb < 2; ++kb)
      #pragma unroll
      for (int r = 0; r < 4; ++r) {
        const float pv = exp2f(sf[kb][r] - mi[r]);
        Pl[wave*640 + (quad*4 + r)*40 + kb*16 + m] =
            (ushort)(__float_as_uint(pv) >> 16);
      }

    // O += P @ V (single K=32 step; nt 8 accumulates the denominator)
    {
      const short8 ap = *(const short8*)&Pl[wave*640 + m*40 + quad*8];
      #pragma unroll
      for (int nt = 0; nt < 9; ++nt) {
        const int row = nt*16 + m;
        const int pos = quad ^ (row & 3);
        const short8 bv = *(const short8*)&Vs[(row*4 + pos)*8];
        Of[nt] = __builtin_amdgcn_mfma_f32_16x16x32_bf16(ap, bv, Of[nt], 0, 0, 0);
      }
    }
  }

  // denominator lives at col 128 -> lanes m==0 of n-tile 8
  if (m == 0) {
    #pragma unroll
    for (int r = 0; r < 4; ++r) li_s[wave*16 + quad*4 + r] = Of[8][r];
  }
  __syncthreads();
  const floatx4 liv = *(const floatx4*)&li_s[wave*16 + quad*4];
  float linv[4];
  #pragma unroll
  for (int r = 0; r < 4; ++r) linv[r] = 1.0f / liv[r];

  ushort* Po = (s == 0) ? Po0 : ((s == 1) ? Po1 : Po2);
  #pragma unroll
  for (int nt = 0; nt < 8; ++nt) {
    #pragma unroll
    for (int r = 0; r < 4; ++r) {
      const int n = n0q + wave*16 + quad*4 + r;
      Po[((size_t)h*N_ + n)*128 + nt*16 + m] = f2bf(Of[nt][r] * linv[r]);
    }
  }
  if (m == 0) {
    #pragma unroll
    for (int r = 0; r < 4; ++r) {
      const int n = n0q + wave*16 + quad*4 + r;
      Pml[(((size_t)s*8 + h)*N_ + n)*2 + 0] = mi[r];
      Pml[(((size_t)s*8 + h)*N_ + n)*2 + 1] = Of[8][r];
    }
  }
}

// ---------------- merge: combine 3 split-K partials (8 elems/thread) ------------
__global__ __launch_bounds__(256) void k_merge(
    const ushort* __restrict__ Po0, const ushort* __restrict__ Po1,
    const ushort* __restrict__ Po2, const float* __restrict__ Pml,
    ushort* __restrict__ out_v_b, ushort* __restrict__ out_g_b)
{
  const int idx = blockIdx.x*256 + threadIdx.x;
  const int c0 = (idx & 15) * 8;
  const int n  = (idx >> 4) & 4095;
  const int h  = idx >> 16;
  const float m1 = Pml[(((size_t)0*8 + h)*N_ + n)*2 + 0];
  const float l1 = Pml[(((size_t)0*8 + h)*N_ + n)*2 + 1];
  const float m2 = Pml[(((size_t)1*8 + h)*N_ + n)*2 + 0];
  const float l2 = Pml[(((size_t)1*8 + h)*N_ + n)*2 + 1];
  const float m3 = Pml[(((size_t)2*8 + h)*N_ + n)*2 + 0];
  const float l3 = Pml[(((size_t)2*8 + h)*N_ + n)*2 + 1];
  const float M = fmaxf(fmaxf(m1, m2), m3);
  const float w1 = exp2f(m1 - M) * l1;
  const float w2 = exp2f(m2 - M) * l2;
  const float w3 = exp2f(m3 - M) * l3;
  const float inv = 1.0f / (w1 + w2 + w3);
  union { short8 v; ushort u[8]; } a, b, c, res;
  a.v = *(const short8*)&Po0[((size_t)h*N_ + n)*128 + c0];
  b.v = *(const short8*)&Po1[((size_t)h*N_ + n)*128 + c0];
  c.v = *(const short8*)&Po2[((size_t)h*N_ + n)*128 + c0];
  #pragma unroll
  for (int j = 0; j < 8; ++j)
    res.u[j] = f2bf((w1*bf2f(a.u[j]) + w2*bf2f(b.u[j]) + w3*bf2f(c.u[j])) * inv);
  if (c0 < 32) {
    *(short8*)&out_v_b[(size_t)n*256 + h*32 + c0] = res.v;
  } else {
    const int j = (c0 - 32) >> 5, cc = (c0 - 32) & 31;
    *(short8*)&out_g_b[((size_t)n*3 + j)*256 + h*32 + cc] = res.v;
  }
}

// ---------------- k5a+k5b fused ----------------
__global__ __launch_bounds__(256) void k56ab(
    const ushort* __restrict__ out_v_b, const ushort* __restrict__ Wngt,
    const float* __restrict__ b_ng, const float* __restrict__ h,
    ushort* __restrict__ tmp_b,
    const ushort* __restrict__ out_g_b, const ushort* __restrict__ Wgoutt,
    const ushort* __restrict__ g_src_b, ushort* __restrict__ gsum_b)
{
  __shared__ __align__(16) ushort As[64*72], Bs[64*72];
  floatx4 acc[4];
  const int lane = threadIdx.x & 63, wave = threadIdx.x >> 6;
  const int quad = lane >> 4, m = lane & 15;
  const int bN = blockIdx.y*64;
  if (blockIdx.x < 64) {
    const int bM = blockIdx.x*64;
    gemm_core<256>(out_v_b, Wngt, bM, bN, acc, As, Bs);
    #pragma unroll
    for (int ct = 0; ct < 4; ++ct) {
      const int c = bN + ct*16 + m;
      #pragma unroll
      for (int r = 0; r < 4; ++r) {
        const int i = bM + wave*16 + quad*4 + r;
        tmp_b[(size_t)i*256 + c] =
            f2bf(acc[ct][r] + b_ng[c] + h[(size_t)i*256 + c] * SQRT_E);
      }
    }
  } else {
    const int bM = (blockIdx.x - 64)*64;
    gemm_core<256>(out_g_b, Wgoutt, bM, bN, acc, As, Bs);
    #pragma unroll
    for (int ct = 0; ct < 4; ++ct) {
      const int c = bN + ct*16 + m;
      #pragma unroll
      for (int r = 0; r < 4; ++r) {
        const int i = bM + wave*16 + quad*4 + r;
        gsum_b[(size_t)i*256 + c] =
            f2bf(acc[ct][r] + bf2f(g_src_b[(size_t)i*256 + c]));
      }
    }
  }
}

// ---------------- k5c+k5d fused ----------------
__global__ __launch_bounds__(256) void k56cd(
    const ushort* __restrict__ tmp_b, const ushort* __restrict__ Whdect,
    const float* __restrict__ b_hdec,
    const ushort* __restrict__ gsum_b, const ushort* __restrict__ Wgdect,
    float* __restrict__ out)
{
  __shared__ __align__(16) ushort As[64*72], Bs[64*72];
  const int t = threadIdx.x;
  const int lane = t & 63, wave = t >> 6;
  const int quad = lane >> 4, m = lane & 15;
  if (blockIdx.x < 64) {
    floatx4 acc[4];
    const int bM = blockIdx.x*64, bN = blockIdx.y*64;
    gemm_core<256>(tmp_b, Whdect, bM, bN, acc, As, Bs);
    #pragma unroll
    for (int ct = 0; ct < 4; ++ct) {
      const int c = bN + ct*16 + m;
      #pragma unroll
      for (int r = 0; r < 4; ++r) {
        const int i = bM + wave*16 + quad*4 + r;
        out[196608 + (size_t)i*256 + c] = acc[ct][r] + b_hdec[c];
      }
    }
  } else if (blockIdx.y == 0) {
    const int bM = (blockIdx.x - 64)*64;
    floatx4 acc = {0.f, 0.f, 0.f, 0.f};
    const int row = t >> 2, kq = (t & 3) * 8;
    for (int k0 = 0; k0 < 256; k0 += 32) {
      __syncthreads();
      *(short8*)&As[row*40 + kq] = *(const short8*)&gsum_b[(size_t)(bM+row)*256 + k0 + kq];
      if (t < 64)
        *(short8*)&Bs[(t>>2)*40 + kq] = *(const short8*)&Wgdect[(size_t)(t>>2)*256 + k0 + kq];
      __syncthreads();
      const short8 af = *(const short8*)&As[(wave*16 + m)*40 + quad*8];
      const short8 bf = *(const short8*)&Bs[m*40 + quad*8];
      acc = __builtin_amdgcn_mfma_f32_16x16x32_bf16(af, bf, acc, 0, 0, 0);
    }
    #pragma unroll
    for (int r = 0; r < 4; ++r)
      out[(size_t)(bM + wave*16 + quad*4 + r)*16 + m] = acc[r];
  }
}

extern "C" void kernel_launch(void* const* d_in, const int* in_sizes, int n_in,
                              void* d_out, int out_size, void* d_ws, size_t ws_size,
                              hipStream_t stream) {
  const float* equ    = (const float*)d_in[0];
  const float* h      = (const float*)d_in[1];
  const float* W_equ  = (const float*)d_in[4];
  const float* W_gproj= (const float*)d_in[5];
  const float* W_vg   = (const float*)d_in[6];
  const float* W_g1   = (const float*)d_in[7];
  const float* b_g1   = (const float*)d_in[8];
  const float* W_g2   = (const float*)d_in[9];
  const float* b_g2   = (const float*)d_in[10];
  const float* W_q    = (const float*)d_in[11];
  const float* b_q    = (const float*)d_in[12];
  const float* W_k    = (const float*)d_in[13];
  const float* b_k    = (const float*)d_in[14];
  const float* W_v    = (const float*)d_in[15];
  const float* b_v    = (const float*)d_in[16];
  const float* W_ng   = (const float*)d_in[17];
  const float* b_ng   = (const float*)d_in[18];
  const float* W_gout = (const float*)d_in[19];
  const float* W_gdec = (const float*)d_in[20];
  const float* W_hdec = (const float*)d_in[21];
  const float* b_hdec = (const float*)d_in[22];
  float* out = (float*)d_out;

  // ---- workspace layout (lifetimes annotated), peak 51.25 MiB (52 proven) ----
  char* wsb = (char*)d_ws;
  constexpr size_t MiB = 1048576;
  float*  q_ws    = (float*) (wsb +  0*MiB);            // 4 MiB [g34 -> k3]
  ushort* kh      = (ushort*)(wsb +  4*MiB);            // 2 MiB [g34 -> k3]
  ushort* kl      = (ushort*)(wsb +  6*MiB);            // 2 MiB [g34 -> k3]
  ushort* vt      = (ushort*)(wsb +  8*MiB);            // 9 MiB [prep/g34 -> k3]
  ushort* h2h     = (ushort*)(wsb + 17*MiB);            // 4 MiB [prep/g2 -> g34]
  ushort* h2l     = (ushort*)(wsb + 21*MiB);            // 4 MiB
  ushort* g_src_b = (ushort*)(wsb + 25*MiB);            // 6 MiB [prep -> g34,k56ab]
  ushort* wbase   = (ushort*)(wsb + 31*MiB);            // 2.875 MiB [prep -> g34]
  ushort* Wg1t = wbase;                                 // 512x1024
  ushort* Wg2t = wbase + 524288;                        // 256x512
  ushort* Wth  = wbase + 655360;                        // 768x512 hi
  ushort* Wtl  = wbase + 1048576;                       // 768x512 lo
  ushort* Wvgt = wbase + 1441792;                       // 256x256
  ushort* wbase2  = (ushort*)(wsb + 34*MiB);            // 0.4 MiB [prep -> k56*]
  ushort* Wngt   = wbase2;                              // 256x256
  ushort* Wgoutt = wbase2 + 65536;                      // 256x256
  ushort* Whdect = wbase2 + 131072;                     // 256x256
  ushort* Wgdect = wbase2 + 196608;                     // 16x256
  ushort* gram_b  = (ushort*)(wsb + 34*MiB + 524288);   // 8 MiB [prep -> g1]
  ushort* hidden  = (ushort*)(wsb + 42*MiB + 524288);   // 4 MiB [g1 -> g2]
  // split-K x3 attention partials (all alias dead regions):
  ushort* Po0     = (ushort*)(wsb + 17*MiB);            // 8 MiB [k3 -> merge] alias h2h/h2l
  ushort* Po1     = (ushort*)(wsb + 34*MiB + 524288);   // 8 MiB [k3 -> merge] alias gram_b
  ushort* Po2     = (ushort*)(wsb + 42*MiB + 524288);   // 8 MiB [k3 -> merge] alias hidden+
  float*  Pml     = (float*) (wsb + 50*MiB + 524288);   // 0.75 MiB [k3 -> merge]
  ushort* out_v_b = (ushort*)(wsb +  4*MiB);            // 2 MiB [merge -> k56ab] alias kh/kl
  ushort* out_g_b = (ushort*)(wsb +  8*MiB);            // 6 MiB [merge -> k56ab] alias vt
  ushort* tmp_b   = (ushort*)(wsb + 42*MiB + 524288);   // 2 MiB [k56ab -> k56cd] alias Po2
  ushort* gsum_b  = (ushort*)(wsb + 34*MiB + 524288);   // 6 MiB [k56ab -> k56cd] alias Po1

  // ---- 1 mega-prep launch (10 transposes + hsplit + vinit + k1) ----
  k_prep<<<11528, 256, 0, stream>>>(
      equ, h, W_equ, W_gproj, W_g1, W_g2, W_q, W_k, W_v,
      W_vg, W_ng, W_gout, W_hdec, W_gdec,
      Wg1t, Wg2t, Wth, Wtl, Wvgt, Wngt, Wgoutt, Whdect, Wgdect,
      h2h, h2l, vt, g_src_b, gram_b);

  // ---- GEMM chain (BK=64 double-pumped cores) ----
  k_g1<<<dim3(64, 8), 256, 0, stream>>>(gram_b, Wg1t, b_g1, hidden);
  k_g2<<<dim3(64, 4), 256, 0, stream>>>(hidden, Wg2t, b_g2, h2h, h2l);
  k_g34<<<dim3(192, 8), 256, 0, stream>>>(h2h, h2l, Wth, Wtl, b_q, b_k, b_v,
                                          g_src_b, Wvgt, q_ws, kh, kl, vt);

  // ---- attention (TK=32, split-K x3) + merge ----
  dim3 g3(64, 8, 3);
  k3_attn<<<g3, 256, 0, stream>>>(q_ws, kh, kl, vt, Po0, Po1, Po2, Pml);
  k_merge<<<2048, 256, 0, stream>>>(Po0, Po1, Po2, Pml, out_v_b, out_g_b);

  // ---- epilogue GEMMs (fused pairs) ----
  k56ab<<<dim3(256, 4), 256, 0, stream>>>(out_v_b, Wngt, b_ng, h, tmp_b,
                                          out_g_b, Wgoutt, g_src_b, gsum_b);
  k56cd<<<dim3(256, 4), 256, 0, stream>>>(tmp_b, Whdect, b_hdec,
                                          gsum_b, Wgdect, out);
}

// Round 13
// 296.832 us; speedup vs baseline: 1.1157x; 1.1157x over previous
//
#include <hip/hip_runtime.h>
#include <hip/hip_bf16.h>

typedef __attribute__((ext_vector_type(8))) short short8;
typedef __attribute__((ext_vector_type(4))) float floatx4;

constexpr int N_ = 4096;
constexpr float SQRT_E = 16.0f;
// q scale folded with log2(e): softmax computed in exp2 domain
constexpr float QSCALE = 0.17677669529663687f * 1.4426950408889634f;

__device__ __forceinline__ ushort f2bf(float x) {
  __hip_bfloat16 h = __float2bfloat16(x);
  return *reinterpret_cast<ushort*>(&h);
}
__device__ __forceinline__ float bf2f(ushort b) {
  unsigned int u = ((unsigned int)b) << 16;
  return __uint_as_float(u);
}

// all 16 lanes of each aligned 16-lane group get the group max (VALU DPP, not LDS)
__device__ __forceinline__ float dpp_max16(float x) {
  int v = __float_as_int(x);
  int y;
  y = __builtin_amdgcn_update_dpp(v, v, 0x128, 0xf, 0xf, false); // row_ror:8
  v = __float_as_int(fmaxf(__int_as_float(v), __int_as_float(y)));
  y = __builtin_amdgcn_update_dpp(v, v, 0x124, 0xf, 0xf, false); // row_ror:4
  v = __float_as_int(fmaxf(__int_as_float(v), __int_as_float(y)));
  y = __builtin_amdgcn_update_dpp(v, v, 0x122, 0xf, 0xf, false); // row_ror:2
  v = __float_as_int(fmaxf(__int_as_float(v), __int_as_float(y)));
  y = __builtin_amdgcn_update_dpp(v, v, 0x121, 0xf, 0xf, false); // row_ror:1
  v = __float_as_int(fmaxf(__int_as_float(v), __int_as_float(y)));
  return __int_as_float(v);
}

// ---------------- transpose helper (device side of mega-prep) ----------------
__device__ __forceinline__ void do_transpose(
    const float* __restrict__ src, ushort* __restrict__ dsth,
    ushort* __restrict__ dstl, int R, int C, int lb, int cb_shift,
    float* smem, int hasLo)
{
  float (*tile)[33] = (float(*)[33])smem;
  const int r0 = (lb >> cb_shift) * 32;
  const int c0 = (lb & ((1 << cb_shift) - 1)) * 32;
  const int tx = threadIdx.x & 31, ty = threadIdx.x >> 5;
  #pragma unroll
  for (int p = 0; p < 4; ++p) {
    const int lr = p*8 + ty;
    tile[lr][tx] = (r0+lr < R && c0+tx < C) ? src[(size_t)(r0+lr)*C + c0 + tx] : 0.f;
  }
  __syncthreads();
  #pragma unroll
  for (int p = 0; p < 4; ++p) {
    const int dc = p*8 + ty;
    if (c0+dc < C && r0+tx < R) {
      const float v = tile[tx][dc];
      const ushort hi = f2bf(v);
      dsth[(size_t)(c0+dc)*R + r0 + tx] = hi;
      if (hasLo) dstl[(size_t)(c0+dc)*R + r0 + tx] = f2bf(v - bf2f(hi));
    }
  }
}

// ---------------- mega-prep: all transposes + hsplit + vinit + k1 in ONE launch --
__global__ __launch_bounds__(256) void k_prep(
    const float* __restrict__ equ, const float* __restrict__ h,
    const float* __restrict__ W_equ, const float* __restrict__ W_gproj,
    const float* __restrict__ W_g1, const float* __restrict__ W_g2,
    const float* __restrict__ W_q, const float* __restrict__ W_k,
    const float* __restrict__ W_v, const float* __restrict__ W_vg,
    const float* __restrict__ W_ng, const float* __restrict__ W_gout,
    const float* __restrict__ W_hdec, const float* __restrict__ W_gdec,
    ushort* __restrict__ Wg1t, ushort* __restrict__ Wg2t,
    ushort* __restrict__ Wth, ushort* __restrict__ Wtl,
    ushort* __restrict__ Wvgt, ushort* __restrict__ Wngt,
    ushort* __restrict__ Wgoutt, ushort* __restrict__ Whdect,
    ushort* __restrict__ Wgdect,
    ushort* __restrict__ h2h, ushort* __restrict__ h2l,
    ushort* __restrict__ vt,
    ushort* __restrict__ g_src_b, ushort* __restrict__ gram_b)
{
  __shared__ __align__(16) float smem[1120];
  const int b = blockIdx.x;
  const int t = threadIdx.x;

  if (b < 512) {            // W_g1 [1024,512] -> Wg1t
    do_transpose(W_g1, Wg1t, nullptr, 1024, 512, b, 4, smem, 0);
  } else if (b < 640) {     // W_g2 [512,256]
    do_transpose(W_g2, Wg2t, nullptr, 512, 256, b-512, 3, smem, 0);
  } else if (b < 768) {     // W_q hi/lo
    do_transpose(W_q, Wth, Wtl, 512, 256, b-640, 3, smem, 1);
  } else if (b < 896) {     // W_k hi/lo
    do_transpose(W_k, Wth + 256*512, Wtl + 256*512, 512, 256, b-768, 3, smem, 1);
  } else if (b < 1024) {    // W_v hi/lo
    do_transpose(W_v, Wth + 512*512, Wtl + 512*512, 512, 256, b-896, 3, smem, 1);
  } else if (b < 1088) {    // W_vg
    do_transpose(W_vg, Wvgt, nullptr, 256, 256, b-1024, 3, smem, 0);
  } else if (b < 1152) {    // W_ng
    do_transpose(W_ng, Wngt, nullptr, 256, 256, b-1088, 3, smem, 0);
  } else if (b < 1216) {    // W_gout
    do_transpose(W_gout, Wgoutt, nullptr, 256, 256, b-1152, 3, smem, 0);
  } else if (b < 1280) {    // W_hdec
    do_transpose(W_hdec, Whdect, nullptr, 256, 256, b-1216, 3, smem, 0);
  } else if (b < 1288) {    // W_gdec [256,16]
    do_transpose(W_gdec, Wgdect, nullptr, 256, 16, b-1280, 0, smem, 0);
  } else if (b < 5384) {    // hsplit: h_src half of h2 (hi/lo)
    const int i = b - 1288;
    const float v = h[(size_t)i*256 + t] * SQRT_E;
    const ushort hi = f2bf(v);
    h2h[(size_t)i*512 + 256 + t] = hi;
    h2l[(size_t)i*512 + 256 + t] = f2bf(v - bf2f(hi));
  } else if (b < 7432) {    // vinit: ones-col + zero ext
    const int idx = (b - 5384)*256 + t;
    const int n = idx & 4095;
    const int c16 = (idx >> 12) & 15;
    const int hh = idx >> 16;
    vt[((size_t)hh*144 + 128 + c16)*N_ + n] = (c16 == 0) ? (ushort)0x3F80 : (ushort)0;
  } else {                  // k1: g_src_b + gram_b
    float* eq   = smem;        // 48
    float* gs   = smem + 48;   // 768
    float* g2p  = smem + 816;  // 96
    float* part = smem + 912;  // 192
    const int i = b - 7432;
    if (t < 48) eq[t] = equ[(size_t)i*48 + t];
    __syncthreads();
    #pragma unroll
    for (int j = 0; j < 3; ++j) {
      float s = 0.f;
      #pragma unroll
      for (int m = 0; m < 16; ++m) s += eq[j*16+m] * W_equ[m*256 + t];
      s *= SQRT_E;
      gs[j*256 + t] = s;
      g_src_b[((size_t)i*3 + j)*256 + t] = f2bf(s);
    }
    __syncthreads();
    if (t < 192) {            // 2-way K-split of the gproj GEMV
      const int o = t % 96, half = t / 96;
      const int j = o >> 5, a = o & 31;
      const int e0 = half * 128;
      float s = 0.f;
      for (int e = 0; e < 128; ++e)
        s += gs[j*256 + e0 + e] * W_gproj[(size_t)(e0+e)*32 + a];
      part[t] = s;
    }
    __syncthreads();
    if (t < 96) g2p[t] = part[t] + part[96 + t];
    __syncthreads();
    #pragma unroll
    for (int r = 0; r < 4; ++r) {
      const int idx = r*256 + t;
      const int a = idx >> 5, bb = idx & 31;
      const float s = g2p[a]*g2p[bb] + g2p[32+a]*g2p[32+bb] + g2p[64+a]*g2p[64+bb];
      gram_b[(size_t)i*1024 + idx] = f2bf(s);
    }
  }
}

// ---------------- GEMM cores: BK=64, double-pumped, register prefetch -----------
template<int KTOT>
__device__ __forceinline__ void gemm_core(
    const ushort* __restrict__ A, const ushort* __restrict__ Bt,
    int bM, int bN, floatx4 acc[4], ushort* As, ushort* Bs)
{
  const int t = threadIdx.x;
  const int wave = t >> 6, lane = t & 63, quad = lane >> 4, m = lane & 15;
  #pragma unroll
  for (int ct = 0; ct < 4; ++ct) acc[ct] = {0.f, 0.f, 0.f, 0.f};
  const int ca = t*2, cb = t*2 + 1;
  const int ra = ca >> 3, pa = ca & 7;
  const int rb = cb >> 3, pb = cb & 7;
  const ushort* pA0 = A  + (size_t)(bM+ra)*KTOT + pa*8;
  const ushort* pA1 = A  + (size_t)(bM+rb)*KTOT + pb*8;
  const ushort* pB0 = Bt + (size_t)(bN+ra)*KTOT + pa*8;
  const ushort* pB1 = Bt + (size_t)(bN+rb)*KTOT + pb*8;
  short8 rA0 = *(const short8*)pA0, rA1 = *(const short8*)pA1;
  short8 rB0 = *(const short8*)pB0, rB1 = *(const short8*)pB1;
  for (int k0 = 0; k0 < KTOT; k0 += 64) {
    __syncthreads();
    *(short8*)&As[ra*72 + pa*8] = rA0;
    *(short8*)&As[rb*72 + pb*8] = rA1;
    *(short8*)&Bs[ra*72 + pa*8] = rB0;
    *(short8*)&Bs[rb*72 + pb*8] = rB1;
    if (k0 + 64 < KTOT) {
      pA0 += 64; pA1 += 64; pB0 += 64; pB1 += 64;
      rA0 = *(const short8*)pA0; rA1 = *(const short8*)pA1;
      rB0 = *(const short8*)pB0; rB1 = *(const short8*)pB1;
    }
    __syncthreads();
    #pragma unroll
    for (int ks = 0; ks < 2; ++ks) {
      const short8 af = *(const short8*)&As[(wave*16 + m)*72 + ks*32 + quad*8];
      #pragma unroll
      for (int ct = 0; ct < 4; ++ct) {
        const short8 bf = *(const short8*)&Bs[(ct*16 + m)*72 + ks*32 + quad*8];
        acc[ct] = __builtin_amdgcn_mfma_f32_16x16x32_bf16(af, bf, acc[ct], 0, 0, 0);
      }
    }
  }
}

template<int KTOT>
__device__ __forceinline__ void gemm_core3(
    const ushort* __restrict__ Ah, const ushort* __restrict__ Al,
    const ushort* __restrict__ Bth, const ushort* __restrict__ Btl,
    int bM, int bN, floatx4 acc[4],
    ushort* Ash, ushort* Asl, ushort* Bsh, ushort* Bsl)
{
  const int t = threadIdx.x;
  const int wave = t >> 6, lane = t & 63, quad = lane >> 4, m = lane & 15;
  #pragma unroll
  for (int ct = 0; ct < 4; ++ct) acc[ct] = {0.f, 0.f, 0.f, 0.f};
  const int ca = t*2, cb = t*2 + 1;
  const int ra = ca >> 3, pa = ca & 7;
  const int rb = cb >> 3, pb = cb & 7;
  const ushort* pAh0 = Ah  + (size_t)(bM+ra)*KTOT + pa*8;
  const ushort* pAh1 = Ah  + (size_t)(bM+rb)*KTOT + pb*8;
  const ushort* pAl0 = Al  + (size_t)(bM+ra)*KTOT + pa*8;
  const ushort* pAl1 = Al  + (size_t)(bM+rb)*KTOT + pb*8;
  const ushort* pBh0 = Bth + (size_t)(bN+ra)*KTOT + pa*8;
  const ushort* pBh1 = Bth + (size_t)(bN+rb)*KTOT + pb*8;
  const ushort* pBl0 = Btl + (size_t)(bN+ra)*KTOT + pa*8;
  const ushort* pBl1 = Btl + (size_t)(bN+rb)*KTOT + pb*8;
  short8 rAh0 = *(const short8*)pAh0, rAh1 = *(const short8*)pAh1;
  short8 rAl0 = *(const short8*)pAl0, rAl1 = *(const short8*)pAl1;
  short8 rBh0 = *(const short8*)pBh0, rBh1 = *(const short8*)pBh1;
  short8 rBl0 = *(const short8*)pBl0, rBl1 = *(const short8*)pBl1;
  for (int k0 = 0; k0 < KTOT; k0 += 64) {
    __syncthreads();
    *(short8*)&Ash[ra*72 + pa*8] = rAh0;
    *(short8*)&Ash[rb*72 + pb*8] = rAh1;
    *(short8*)&Asl[ra*72 + pa*8] = rAl0;
    *(short8*)&Asl[rb*72 + pb*8] = rAl1;
    *(short8*)&Bsh[ra*72 + pa*8] = rBh0;
    *(short8*)&Bsh[rb*72 + pb*8] = rBh1;
    *(short8*)&Bsl[ra*72 + pa*8] = rBl0;
    *(short8*)&Bsl[rb*72 + pb*8] = rBl1;
    if (k0 + 64 < KTOT) {
      pAh0 += 64; pAh1 += 64; pAl0 += 64; pAl1 += 64;
      pBh0 += 64; pBh1 += 64; pBl0 += 64; pBl1 += 64;
      rAh0 = *(const short8*)pAh0; rAh1 = *(const short8*)pAh1;
      rAl0 = *(const short8*)pAl0; rAl1 = *(const short8*)pAl1;
      rBh0 = *(const short8*)pBh0; rBh1 = *(const short8*)pBh1;
      rBl0 = *(const short8*)pBl0; rBl1 = *(const short8*)pBl1;
    }
    __syncthreads();
    #pragma unroll
    for (int ks = 0; ks < 2; ++ks) {
      const short8 ah = *(const short8*)&Ash[(wave*16 + m)*72 + ks*32 + quad*8];
      const short8 al = *(const short8*)&Asl[(wave*16 + m)*72 + ks*32 + quad*8];
      #pragma unroll
      for (int ct = 0; ct < 4; ++ct) {
        const short8 bh = *(const short8*)&Bsh[(ct*16 + m)*72 + ks*32 + quad*8];
        const short8 bl = *(const short8*)&Bsl[(ct*16 + m)*72 + ks*32 + quad*8];
        acc[ct] = __builtin_amdgcn_mfma_f32_16x16x32_bf16(ah, bl, acc[ct], 0, 0, 0);
        acc[ct] = __builtin_amdgcn_mfma_f32_16x16x32_bf16(al, bh, acc[ct], 0, 0, 0);
        acc[ct] = __builtin_amdgcn_mfma_f32_16x16x32_bf16(ah, bh, acc[ct], 0, 0, 0);
      }
    }
  }
}

// G1: hidden = relu(gram @ W_g1 + b_g1)
__global__ __launch_bounds__(256) void k_g1(
    const ushort* __restrict__ gram_b, const ushort* __restrict__ Wg1t,
    const float* __restrict__ b_g1, ushort* __restrict__ hidden)
{
  __shared__ __align__(16) ushort As[64*72], Bs[64*72];
  floatx4 acc[4];
  const int bM = blockIdx.x*64, bN = blockIdx.y*64;
  gemm_core<1024>(gram_b, Wg1t, bM, bN, acc, As, Bs);
  const int lane = threadIdx.x & 63, wave = threadIdx.x >> 6;
  const int quad = lane >> 4, m = lane & 15;
  #pragma unroll
  for (int ct = 0; ct < 4; ++ct) {
    const int c = bN + ct*16 + m;
    #pragma unroll
    for (int r = 0; r < 4; ++r) {
      const int i = bM + wave*16 + quad*4 + r;
      hidden[(size_t)i*512 + c] = f2bf(fmaxf(acc[ct][r] + b_g1[c], 0.f));
    }
  }
}

// G2: g2 = hidden @ W_g2 + b_g2 -> hi/lo into h2 cols 0..255
__global__ __launch_bounds__(256) void k_g2(
    const ushort* __restrict__ hidden, const ushort* __restrict__ Wg2t,
    const float* __restrict__ b_g2, ushort* __restrict__ h2h, ushort* __restrict__ h2l)
{
  __shared__ __align__(16) ushort As[64*72], Bs[64*72];
  floatx4 acc[4];
  const int bM = blockIdx.x*64, bN = blockIdx.y*64;
  gemm_core<512>(hidden, Wg2t, bM, bN, acc, As, Bs);
  const int lane = threadIdx.x & 63, wave = threadIdx.x >> 6;
  const int quad = lane >> 4, m = lane & 15;
  #pragma unroll
  for (int ct = 0; ct < 4; ++ct) {
    const int c = bN + ct*16 + m;
    #pragma unroll
    for (int r = 0; r < 4; ++r) {
      const int i = bM + wave*16 + quad*4 + r;
      const float s = acc[ct][r] + b_g2[c];
      const ushort hi = f2bf(s);
      h2h[(size_t)i*512 + c] = hi;
      h2l[(size_t)i*512 + c] = f2bf(s - bf2f(hi));
    }
  }
}

// G3+G4 fused: q/k hi/lo 3-term; v 1-term; vg 1-term
__global__ __launch_bounds__(256) void k_g34(
    const ushort* __restrict__ h2h, const ushort* __restrict__ h2l,
    const ushort* __restrict__ Wth, const ushort* __restrict__ Wtl,
    const float* __restrict__ b_q, const float* __restrict__ b_k,
    const float* __restrict__ b_v,
    const ushort* __restrict__ g_src_b, const ushort* __restrict__ Wvgt,
    float* __restrict__ q_ws, ushort* __restrict__ kh, ushort* __restrict__ kl,
    ushort* __restrict__ vt)
{
  __shared__ __align__(16) ushort S0[64*72], S1[64*72], S2[64*72], S3[64*72];
  const int lb = blockIdx.y*192 + blockIdx.x;     // grid (192,8) = 1536
  const int lane = threadIdx.x & 63, wave = threadIdx.x >> 6;
  const int quad = lane >> 4, m = lane & 15;
  floatx4 acc[4];
  if (lb < 768) {
    const int bM = (lb & 63)*64, bN = (lb >> 6)*64;
    if (bN < 512) {
      gemm_core3<512>(h2h, h2l, Wth, Wtl, bM, bN, acc, S0, S1, S2, S3);
      #pragma unroll
      for (int ct = 0; ct < 4; ++ct) {
        const int c = bN + ct*16 + m;
        #pragma unroll
        for (int r = 0; r < 4; ++r) {
          const int i = bM + wave*16 + quad*4 + r;
          if (c < 256) {
            const float s = acc[ct][r] + b_q[c];
            q_ws[((size_t)(c >> 5)*N_ + i)*32 + (c & 31)] = s * QSCALE;
          } else {
            const int cc = c - 256;
            const float s = acc[ct][r] + b_k[cc];
            const ushort hi = f2bf(s);
            kh[((size_t)(cc >> 5)*N_ + i)*32 + (cc & 31)] = hi;
            kl[((size_t)(cc >> 5)*N_ + i)*32 + (cc & 31)] = f2bf(s - bf2f(hi));
          }
        }
      }
    } else {
      gemm_core<512>(h2h, Wth, bM, bN, acc, S0, S1);
      #pragma unroll
      for (int ct = 0; ct < 4; ++ct) {
        const int cc = bN + ct*16 + m - 512;
        #pragma unroll
        for (int r = 0; r < 4; ++r) {
          const int i = bM + wave*16 + quad*4 + r;
          const float s = acc[ct][r] + b_v[cc];
          vt[((size_t)(cc >> 5)*144 + (cc & 31))*N_ + i] = f2bf(s);
        }
      }
    }
  } else {
    const int lb2 = lb - 768;
    const int bM = (lb2 >> 2)*64, bN = (lb2 & 3)*64;
    gemm_core<256>(g_src_b, Wvgt, bM, bN, acc, S0, S1);
    #pragma unroll
    for (int ct = 0; ct < 4; ++ct) {
      const int c = bN + ct*16 + m;
      const int hh = c >> 5, d = c & 31;
      #pragma unroll
      for (int r = 0; r < 4; ++r) {
        const int i3 = bM + wave*16 + quad*4 + r;
        const int i = i3 / 3, j = i3 - 3*i;
        vt[((size_t)hh*144 + 32 + j*32 + d)*N_ + i] = f2bf(acc[ct][r]);
      }
    }
  }
}

// ---------------- K3: MFMA flash attention (TK=64, round-10 verified) -----------
// Split-K x3 (tiles 22/21/21), register-prefetch, ones-col denominator,
// deferred rescale, DPP max, truncated-bf16 P, exp2-domain softmax.
__global__ __launch_bounds__(256, 4) void k3_attn(
    const float* __restrict__ q_ws, const ushort* __restrict__ kh,
    const ushort* __restrict__ kl, const ushort* __restrict__ vt,
    ushort* __restrict__ Po0, ushort* __restrict__ Po1, ushort* __restrict__ Po2,
    float* __restrict__ Pml)
{
  __shared__ __align__(16) ushort Khs[64*40], Kls[64*40];
  __shared__ __align__(16) ushort Vs[144*64];
  __shared__ __align__(16) ushort Pl[4*16*72];
  __shared__ float li_s[64];

  const int t    = threadIdx.x;
  const int wave = t >> 6;
  const int lane = t & 63;
  const int quad = lane >> 4;
  const int m    = lane & 15;
  const int h    = blockIdx.y;
  const int s    = blockIdx.z;
  const int n0q  = blockIdx.x * 64;

  const int ktb = (s == 0) ? 0  : (s == 1 ? 22 : 43);
  const int kte = (s == 0) ? 22 : (s == 1 ? 43 : 64);

  union { short8 v; ushort u[8]; } Aqh, Aql;
  {
    const float* qp = q_ws + ((size_t)h*N_ + n0q + wave*16 + m)*32 + quad*8;
    #pragma unroll
    for (int jj = 0; jj < 8; ++jj) {
      const float x = qp[jj];
      const ushort hi = f2bf(x);
      Aqh.u[jj] = hi;
      Aql.u[jj] = f2bf(x - bf2f(hi));
    }
  }

  floatx4 Of[9];
  #pragma unroll
  for (int nt = 0; nt < 9; ++nt) Of[nt] = {0.f, 0.f, 0.f, 0.f};
  float mi[4];
  #pragma unroll
  for (int r = 0; r < 4; ++r) mi[r] = -3.0e38f;

  const int krow = t >> 2, kch = (t & 3) * 8;

  const ushort* pKh = kh + ((size_t)h*N_ + ktb*64 + krow)*32 + kch;
  const ushort* pKl = kl + ((size_t)h*N_ + ktb*64 + krow)*32 + kch;
  const ushort* pV[4];
  int wV[4];
  #pragma unroll
  for (int p = 0; p < 4; ++p) {
    const int idx = p*256 + t, row = idx >> 3, g = idx & 7;
    pV[p] = vt + ((size_t)h*144 + row)*N_ + ktb*64 + g*8;
    wV[p] = (row*8 + (g ^ (row & 7)))*8;
  }
  const ushort* pV4 = nullptr;
  int wV4 = 0;
  if (t < 128) {
    const int idx = 1024 + t, row = idx >> 3, g = idx & 7;
    pV4 = vt + ((size_t)h*144 + row)*N_ + ktb*64 + g*8;
    wV4 = (row*8 + (g ^ (row & 7)))*8;
  }

  short8 rK0 = *(const short8*)pKh;
  short8 rK1 = *(const short8*)pKl;
  short8 rV[4], rV4e;
  #pragma unroll
  for (int p = 0; p < 4; ++p) rV[p] = *(const short8*)pV[p];
  if (t < 128) rV4e = *(const short8*)pV4;

  for (int kt = ktb; kt < kte; ++kt) {
    __syncthreads();
    *(short8*)&Khs[krow*40 + kch] = rK0;
    *(short8*)&Kls[krow*40 + kch] = rK1;
    #pragma unroll
    for (int p = 0; p < 4; ++p) *(short8*)&Vs[wV[p]] = rV[p];
    if (t < 128) *(short8*)&Vs[wV4] = rV4e;
    if (kt + 1 < kte) {
      pKh += 2048; pKl += 2048;
      rK0 = *(const short8*)pKh;
      rK1 = *(const short8*)pKl;
      #pragma unroll
      for (int p = 0; p < 4; ++p) { pV[p] += 64; rV[p] = *(const short8*)pV[p]; }
      if (t < 128) { pV4 += 64; rV4e = *(const short8*)pV4; }
    }
    __syncthreads();

    floatx4 sf[4];
    #pragma unroll
    for (int kb = 0; kb < 4; ++kb) {
      const short8 bkh = *(const short8*)&Khs[(kb*16 + m)*40 + quad*8];
      const short8 bkl = *(const short8*)&Kls[(kb*16 + m)*40 + quad*8];
      floatx4 sv = {0.f, 0.f, 0.f, 0.f};
      sv = __builtin_amdgcn_mfma_f32_16x16x32_bf16(Aqh.v, bkl, sv, 0, 0, 0);
      sv = __builtin_amdgcn_mfma_f32_16x16x32_bf16(Aql.v, bkh, sv, 0, 0, 0);
      sv = __builtin_amdgcn_mfma_f32_16x16x32_bf16(Aqh.v, bkh, sv, 0, 0, 0);
      sf[kb] = sv;
    }

    float tm[4];
    bool need = false;
    #pragma unroll
    for (int r = 0; r < 4; ++r) {
      float nm = fmaxf(fmaxf(sf[0][r], sf[1][r]), fmaxf(sf[2][r], sf[3][r]));
      tm[r] = dpp_max16(nm);
      need |= (tm[r] > mi[r] + 20.f);
    }
    if (__any(need)) {
      #pragma unroll
      for (int r = 0; r < 4; ++r) {
        const float mn = fmaxf(mi[r], tm[r]);
        const float al = exp2f(mi[r] - mn);
        mi[r] = mn;
        #pragma unroll
        for (int nt = 0; nt < 9; ++nt) Of[nt][r] *= al;
      }
    }
    #pragma unroll
    for (int kb = 0; kb < 4; ++kb)
      #pragma unroll
      for (int r = 0; r < 4; ++r) {
        const float pv = exp2f(sf[kb][r] - mi[r]);
        Pl[wave*1152 + (quad*4 + r)*72 + kb*16 + m] =
            (ushort)(__float_as_uint(pv) >> 16);
      }

    #pragma unroll
    for (int ks = 0; ks < 2; ++ks) {
      const short8 ap = *(const short8*)&Pl[wave*1152 + m*72 + ks*32 + quad*8];
      #pragma unroll
      for (int nt = 0; nt < 9; ++nt) {
        const int row = nt*16 + m;
        const int pos = (ks*4 + quad) ^ (row & 7);
        const short8 bv = *(const short8*)&Vs[(row*8 + pos)*8];
        Of[nt] = __builtin_amdgcn_mfma_f32_16x16x32_bf16(ap, bv, Of[nt], 0, 0, 0);
      }
    }
  }

  if (m == 0) {
    #pragma unroll
    for (int r = 0; r < 4; ++r) li_s[wave*16 + quad*4 + r] = Of[8][r];
  }
  __syncthreads();
  const floatx4 liv = *(const floatx4*)&li_s[wave*16 + quad*4];
  float linv[4];
  #pragma unroll
  for (int r = 0; r < 4; ++r) linv[r] = 1.0f / liv[r];

  ushort* Po = (s == 0) ? Po0 : ((s == 1) ? Po1 : Po2);
  #pragma unroll
  for (int nt = 0; nt < 8; ++nt) {
    #pragma unroll
    for (int r = 0; r < 4; ++r) {
      const int n = n0q + wave*16 + quad*4 + r;
      Po[((size_t)h*N_ + n)*128 + nt*16 + m] = f2bf(Of[nt][r] * linv[r]);
    }
  }
  if (m == 0) {
    #pragma unroll
    for (int r = 0; r < 4; ++r) {
      const int n = n0q + wave*16 + quad*4 + r;
      Pml[(((size_t)s*8 + h)*N_ + n)*2 + 0] = mi[r];
      Pml[(((size_t)s*8 + h)*N_ + n)*2 + 1] = Of[8][r];
    }
  }
}

// ---------------- merge: combine 3 split-K partials (8 elems/thread) ------------
__global__ __launch_bounds__(256) void k_merge(
    const ushort* __restrict__ Po0, const ushort* __restrict__ Po1,
    const ushort* __restrict__ Po2, const float* __restrict__ Pml,
    ushort* __restrict__ out_v_b, ushort* __restrict__ out_g_b)
{
  const int idx = blockIdx.x*256 + threadIdx.x;
  const int c0 = (idx & 15) * 8;
  const int n  = (idx >> 4) & 4095;
  const int h  = idx >> 16;
  const float m1 = Pml[(((size_t)0*8 + h)*N_ + n)*2 + 0];
  const float l1 = Pml[(((size_t)0*8 + h)*N_ + n)*2 + 1];
  const float m2 = Pml[(((size_t)1*8 + h)*N_ + n)*2 + 0];
  const float l2 = Pml[(((size_t)1*8 + h)*N_ + n)*2 + 1];
  const float m3 = Pml[(((size_t)2*8 + h)*N_ + n)*2 + 0];
  const float l3 = Pml[(((size_t)2*8 + h)*N_ + n)*2 + 1];
  const float M = fmaxf(fmaxf(m1, m2), m3);
  const float w1 = exp2f(m1 - M) * l1;
  const float w2 = exp2f(m2 - M) * l2;
  const float w3 = exp2f(m3 - M) * l3;
  const float inv = 1.0f / (w1 + w2 + w3);
  union { short8 v; ushort u[8]; } a, b, c, res;
  a.v = *(const short8*)&Po0[((size_t)h*N_ + n)*128 + c0];
  b.v = *(const short8*)&Po1[((size_t)h*N_ + n)*128 + c0];
  c.v = *(const short8*)&Po2[((size_t)h*N_ + n)*128 + c0];
  #pragma unroll
  for (int j = 0; j < 8; ++j)
    res.u[j] = f2bf((w1*bf2f(a.u[j]) + w2*bf2f(b.u[j]) + w3*bf2f(c.u[j])) * inv);
  if (c0 < 32) {
    *(short8*)&out_v_b[(size_t)n*256 + h*32 + c0] = res.v;
  } else {
    const int j = (c0 - 32) >> 5, cc = (c0 - 32) & 31;
    *(short8*)&out_g_b[((size_t)n*3 + j)*256 + h*32 + cc] = res.v;
  }
}

// ---------------- k5a+k5b fused ----------------
__global__ __launch_bounds__(256) void k56ab(
    const ushort* __restrict__ out_v_b, const ushort* __restrict__ Wngt,
    const float* __restrict__ b_ng, const float* __restrict__ h,
    ushort* __restrict__ tmp_b,
    const ushort* __restrict__ out_g_b, const ushort* __restrict__ Wgoutt,
    const ushort* __restrict__ g_src_b, ushort* __restrict__ gsum_b)
{
  __shared__ __align__(16) ushort As[64*72], Bs[64*72];
  floatx4 acc[4];
  const int lane = threadIdx.x & 63, wave = threadIdx.x >> 6;
  const int quad = lane >> 4, m = lane & 15;
  const int bN = blockIdx.y*64;
  if (blockIdx.x < 64) {
    const int bM = blockIdx.x*64;
    gemm_core<256>(out_v_b, Wngt, bM, bN, acc, As, Bs);
    #pragma unroll
    for (int ct = 0; ct < 4; ++ct) {
      const int c = bN + ct*16 + m;
      #pragma unroll
      for (int r = 0; r < 4; ++r) {
        const int i = bM + wave*16 + quad*4 + r;
        tmp_b[(size_t)i*256 + c] =
            f2bf(acc[ct][r] + b_ng[c] + h[(size_t)i*256 + c] * SQRT_E);
      }
    }
  } else {
    const int bM = (blockIdx.x - 64)*64;
    gemm_core<256>(out_g_b, Wgoutt, bM, bN, acc, As, Bs);
    #pragma unroll
    for (int ct = 0; ct < 4; ++ct) {
      const int c = bN + ct*16 + m;
      #pragma unroll
      for (int r = 0; r < 4; ++r) {
        const int i = bM + wave*16 + quad*4 + r;
        gsum_b[(size_t)i*256 + c] =
            f2bf(acc[ct][r] + bf2f(g_src_b[(size_t)i*256 + c]));
      }
    }
  }
}

// ---------------- k5c+k5d fused ----------------
__global__ __launch_bounds__(256) void k56cd(
    const ushort* __restrict__ tmp_b, const ushort* __restrict__ Whdect,
    const float* __restrict__ b_hdec,
    const ushort* __restrict__ gsum_b, const ushort* __restrict__ Wgdect,
    float* __restrict__ out)
{
  __shared__ __align__(16) ushort As[64*72], Bs[64*72];
  const int t = threadIdx.x;
  const int lane = t & 63, wave = t >> 6;
  const int quad = lane >> 4, m = lane & 15;
  if (blockIdx.x < 64) {
    floatx4 acc[4];
    const int bM = blockIdx.x*64, bN = blockIdx.y*64;
    gemm_core<256>(tmp_b, Whdect, bM, bN, acc, As, Bs);
    #pragma unroll
    for (int ct = 0; ct < 4; ++ct) {
      const int c = bN + ct*16 + m;
      #pragma unroll
      for (int r = 0; r < 4; ++r) {
        const int i = bM + wave*16 + quad*4 + r;
        out[196608 + (size_t)i*256 + c] = acc[ct][r] + b_hdec[c];
      }
    }
  } else if (blockIdx.y == 0) {
    const int bM = (blockIdx.x - 64)*64;
    floatx4 acc = {0.f, 0.f, 0.f, 0.f};
    const int row = t >> 2, kq = (t & 3) * 8;
    for (int k0 = 0; k0 < 256; k0 += 32) {
      __syncthreads();
      *(short8*)&As[row*40 + kq] = *(const short8*)&gsum_b[(size_t)(bM+row)*256 + k0 + kq];
      if (t < 64)
        *(short8*)&Bs[(t>>2)*40 + kq] = *(const short8*)&Wgdect[(size_t)(t>>2)*256 + k0 + kq];
      __syncthreads();
      const short8 af = *(const short8*)&As[(wave*16 + m)*40 + quad*8];
      const short8 bf = *(const short8*)&Bs[m*40 + quad*8];
      acc = __builtin_amdgcn_mfma_f32_16x16x32_bf16(af, bf, acc, 0, 0, 0);
    }
    #pragma unroll
    for (int r = 0; r < 4; ++r)
      out[(size_t)(bM + wave*16 + quad*4 + r)*16 + m] = acc[r];
  }
}

extern "C" void kernel_launch(void* const* d_in, const int* in_sizes, int n_in,
                              void* d_out, int out_size, void* d_ws, size_t ws_size,
                              hipStream_t stream) {
  const float* equ    = (const float*)d_in[0];
  const float* h      = (const float*)d_in[1];
  const float* W_equ  = (const float*)d_in[4];
  const float* W_gproj= (const float*)d_in[5];
  const float* W_vg   = (const float*)d_in[6];
  const float* W_g1   = (const float*)d_in[7];
  const float* b_g1   = (const float*)d_in[8];
  const float* W_g2   = (const float*)d_in[9];
  const float* b_g2   = (const float*)d_in[10];
  const float* W_q    = (const float*)d_in[11];
  const float* b_q    = (const float*)d_in[12];
  const float* W_k    = (const float*)d_in[13];
  const float* b_k    = (const float*)d_in[14];
  const float* W_v    = (const float*)d_in[15];
  const float* b_v    = (const float*)d_in[16];
  const float* W_ng   = (const float*)d_in[17];
  const float* b_ng   = (const float*)d_in[18];
  const float* W_gout = (const float*)d_in[19];
  const float* W_gdec = (const float*)d_in[20];
  const float* W_hdec = (const float*)d_in[21];
  const float* b_hdec = (const float*)d_in[22];
  float* out = (float*)d_out;

  // ---- workspace layout (lifetimes annotated), peak 51.25 MiB (52 proven) ----
  char* wsb = (char*)d_ws;
  constexpr size_t MiB = 1048576;
  float*  q_ws    = (float*) (wsb +  0*MiB);            // 4 MiB [g34 -> k3]
  ushort* kh      = (ushort*)(wsb +  4*MiB);            // 2 MiB [g34 -> k3]
  ushort* kl      = (ushort*)(wsb +  6*MiB);            // 2 MiB [g34 -> k3]
  ushort* vt      = (ushort*)(wsb +  8*MiB);            // 9 MiB [prep/g34 -> k3]
  ushort* h2h     = (ushort*)(wsb + 17*MiB);            // 4 MiB [prep/g2 -> g34]
  ushort* h2l     = (ushort*)(wsb + 21*MiB);            // 4 MiB
  ushort* g_src_b = (ushort*)(wsb + 25*MiB);            // 6 MiB [prep -> g34,k56ab]
  ushort* wbase   = (ushort*)(wsb + 31*MiB);            // 2.875 MiB [prep -> g34]
  ushort* Wg1t = wbase;                                 // 512x1024
  ushort* Wg2t = wbase + 524288;                        // 256x512
  ushort* Wth  = wbase + 655360;                        // 768x512 hi
  ushort* Wtl  = wbase + 1048576;                       // 768x512 lo
  ushort* Wvgt = wbase + 1441792;                       // 256x256
  ushort* wbase2  = (ushort*)(wsb + 34*MiB);            // 0.4 MiB [prep -> k56*]
  ushort* Wngt   = wbase2;                              // 256x256
  ushort* Wgoutt = wbase2 + 65536;                      // 256x256
  ushort* Whdect = wbase2 + 131072;                     // 256x256
  ushort* Wgdect = wbase2 + 196608;                     // 16x256
  ushort* gram_b  = (ushort*)(wsb + 34*MiB + 524288);   // 8 MiB [prep -> g1]
  ushort* hidden  = (ushort*)(wsb + 42*MiB + 524288);   // 4 MiB [g1 -> g2]
  // split-K x3 attention partials (all alias dead regions):
  ushort* Po0     = (ushort*)(wsb + 17*MiB);            // 8 MiB [k3 -> merge] alias h2h/h2l
  ushort* Po1     = (ushort*)(wsb + 34*MiB + 524288);   // 8 MiB [k3 -> merge] alias gram_b
  ushort* Po2     = (ushort*)(wsb + 42*MiB + 524288);   // 8 MiB [k3 -> merge] alias hidden+
  float*  Pml     = (float*) (wsb + 50*MiB + 524288);   // 0.75 MiB [k3 -> merge]
  ushort* out_v_b = (ushort*)(wsb +  4*MiB);            // 2 MiB [merge -> k56ab] alias kh/kl
  ushort* out_g_b = (ushort*)(wsb +  8*MiB);            // 6 MiB [merge -> k56ab] alias vt
  ushort* tmp_b   = (ushort*)(wsb + 42*MiB + 524288);   // 2 MiB [k56ab -> k56cd] alias Po2
  ushort* gsum_b  = (ushort*)(wsb + 34*MiB + 524288);   // 6 MiB [k56ab -> k56cd] alias Po1

  // ---- 1 mega-prep launch (10 transposes + hsplit + vinit + k1) ----
  k_prep<<<11528, 256, 0, stream>>>(
      equ, h, W_equ, W_gproj, W_g1, W_g2, W_q, W_k, W_v,
      W_vg, W_ng, W_gout, W_hdec, W_gdec,
      Wg1t, Wg2t, Wth, Wtl, Wvgt, Wngt, Wgoutt, Whdect, Wgdect,
      h2h, h2l, vt, g_src_b, gram_b);

  // ---- GEMM chain (BK=64 double-pumped cores) ----
  k_g1<<<dim3(64, 8), 256, 0, stream>>>(gram_b, Wg1t, b_g1, hidden);
  k_g2<<<dim3(64, 4), 256, 0, stream>>>(hidden, Wg2t, b_g2, h2h, h2l);
  k_g34<<<dim3(192, 8), 256, 0, stream>>>(h2h, h2l, Wth, Wtl, b_q, b_k, b_v,
                                          g_src_b, Wvgt, q_ws, kh, kl, vt);

  // ---- attention (TK=64, split-K x3) + merge ----
  dim3 g3(64, 8, 3);
  k3_attn<<<g3, 256, 0, stream>>>(q_ws, kh, kl, vt, Po0, Po1, Po2, Pml);
  k_merge<<<2048, 256, 0, stream>>>(Po0, Po1, Po2, Pml, out_v_b, out_g_b);

  // ---- epilogue GEMMs (fused pairs) ----
  k56ab<<<dim3(256, 4), 256, 0, stream>>>(out_v_b, Wngt, b_ng, h, tmp_b,
                                          out_g_b, Wgoutt, g_src_b, gsum_b);
  k56cd<<<dim3(256, 4), 256, 0, stream>>>(tmp_b, Whdect, b_hdec,
                                          gsum_b, Wgdect, out);
}

// Round 14
// 284.429 us; speedup vs baseline: 1.1644x; 1.0436x over previous
//
#include <hip/hip_runtime.h>
#include <hip/hip_bf16.h>

typedef __attribute__((ext_vector_type(8))) short short8;
typedef __attribute__((ext_vector_type(4))) float floatx4;

constexpr int N_ = 4096;
constexpr float SQRT_E = 16.0f;
// q scale folded with log2(e): softmax computed in exp2 domain
constexpr float QSCALE = 0.17677669529663687f * 1.4426950408889634f;

__device__ __forceinline__ ushort f2bf(float x) {
  __hip_bfloat16 h = __float2bfloat16(x);
  return *reinterpret_cast<ushort*>(&h);
}
__device__ __forceinline__ float bf2f(ushort b) {
  unsigned int u = ((unsigned int)b) << 16;
  return __uint_as_float(u);
}

// all 16 lanes of each aligned 16-lane group get the group max (VALU DPP, not LDS)
__device__ __forceinline__ float dpp_max16(float x) {
  int v = __float_as_int(x);
  int y;
  y = __builtin_amdgcn_update_dpp(v, v, 0x128, 0xf, 0xf, false); // row_ror:8
  v = __float_as_int(fmaxf(__int_as_float(v), __int_as_float(y)));
  y = __builtin_amdgcn_update_dpp(v, v, 0x124, 0xf, 0xf, false); // row_ror:4
  v = __float_as_int(fmaxf(__int_as_float(v), __int_as_float(y)));
  y = __builtin_amdgcn_update_dpp(v, v, 0x122, 0xf, 0xf, false); // row_ror:2
  v = __float_as_int(fmaxf(__int_as_float(v), __int_as_float(y)));
  y = __builtin_amdgcn_update_dpp(v, v, 0x121, 0xf, 0xf, false); // row_ror:1
  v = __float_as_int(fmaxf(__int_as_float(v), __int_as_float(y)));
  return __int_as_float(v);
}

// ---------------- transpose helper (device side of mega-prep) ----------------
__device__ __forceinline__ void do_transpose(
    const float* __restrict__ src, ushort* __restrict__ dsth,
    ushort* __restrict__ dstl, int R, int C, int lb, int cb_shift,
    float* smem, int hasLo)
{
  float (*tile)[33] = (float(*)[33])smem;
  const int r0 = (lb >> cb_shift) * 32;
  const int c0 = (lb & ((1 << cb_shift) - 1)) * 32;
  const int tx = threadIdx.x & 31, ty = threadIdx.x >> 5;
  #pragma unroll
  for (int p = 0; p < 4; ++p) {
    const int lr = p*8 + ty;
    tile[lr][tx] = (r0+lr < R && c0+tx < C) ? src[(size_t)(r0+lr)*C + c0 + tx] : 0.f;
  }
  __syncthreads();
  #pragma unroll
  for (int p = 0; p < 4; ++p) {
    const int dc = p*8 + ty;
    if (c0+dc < C && r0+tx < R) {
      const float v = tile[tx][dc];
      const ushort hi = f2bf(v);
      dsth[(size_t)(c0+dc)*R + r0 + tx] = hi;
      if (hasLo) dstl[(size_t)(c0+dc)*R + r0 + tx] = f2bf(v - bf2f(hi));
    }
  }
}

// ---------------- mega-prep: all transposes + hsplit + vinit + k1 in ONE launch --
__global__ __launch_bounds__(256) void k_prep(
    const float* __restrict__ equ, const float* __restrict__ h,
    const float* __restrict__ W_equ, const float* __restrict__ W_gproj,
    const float* __restrict__ W_g1, const float* __restrict__ W_g2,
    const float* __restrict__ W_q, const float* __restrict__ W_k,
    const float* __restrict__ W_v, const float* __restrict__ W_vg,
    const float* __restrict__ W_ng, const float* __restrict__ W_gout,
    const float* __restrict__ W_hdec, const float* __restrict__ W_gdec,
    ushort* __restrict__ Wg1t, ushort* __restrict__ Wg2t,
    ushort* __restrict__ Wth, ushort* __restrict__ Wtl,
    ushort* __restrict__ Wvgt, ushort* __restrict__ Wngt,
    ushort* __restrict__ Wgoutt, ushort* __restrict__ Whdect,
    ushort* __restrict__ Wgdect,
    ushort* __restrict__ h2h, ushort* __restrict__ h2l,
    ushort* __restrict__ vt,
    ushort* __restrict__ g_src_b, ushort* __restrict__ gram_b)
{
  __shared__ __align__(16) float smem[1120];
  const int b = blockIdx.x;
  const int t = threadIdx.x;

  if (b < 512) {            // W_g1 [1024,512] -> Wg1t
    do_transpose(W_g1, Wg1t, nullptr, 1024, 512, b, 4, smem, 0);
  } else if (b < 640) {     // W_g2 [512,256]
    do_transpose(W_g2, Wg2t, nullptr, 512, 256, b-512, 3, smem, 0);
  } else if (b < 768) {     // W_q hi/lo
    do_transpose(W_q, Wth, Wtl, 512, 256, b-640, 3, smem, 1);
  } else if (b < 896) {     // W_k hi/lo
    do_transpose(W_k, Wth + 256*512, Wtl + 256*512, 512, 256, b-768, 3, smem, 1);
  } else if (b < 1024) {    // W_v hi/lo
    do_transpose(W_v, Wth + 512*512, Wtl + 512*512, 512, 256, b-896, 3, smem, 1);
  } else if (b < 1088) {    // W_vg
    do_transpose(W_vg, Wvgt, nullptr, 256, 256, b-1024, 3, smem, 0);
  } else if (b < 1152) {    // W_ng
    do_transpose(W_ng, Wngt, nullptr, 256, 256, b-1088, 3, smem, 0);
  } else if (b < 1216) {    // W_gout
    do_transpose(W_gout, Wgoutt, nullptr, 256, 256, b-1152, 3, smem, 0);
  } else if (b < 1280) {    // W_hdec
    do_transpose(W_hdec, Whdect, nullptr, 256, 256, b-1216, 3, smem, 0);
  } else if (b < 1288) {    // W_gdec [256,16]
    do_transpose(W_gdec, Wgdect, nullptr, 256, 16, b-1280, 0, smem, 0);
  } else if (b < 5384) {    // hsplit: h_src half of h2 (hi/lo)
    const int i = b - 1288;
    const float v = h[(size_t)i*256 + t] * SQRT_E;
    const ushort hi = f2bf(v);
    h2h[(size_t)i*512 + 256 + t] = hi;
    h2l[(size_t)i*512 + 256 + t] = f2bf(v - bf2f(hi));
  } else if (b < 7432) {    // vinit: ones-col + zero ext
    const int idx = (b - 5384)*256 + t;
    const int n = idx & 4095;
    const int c16 = (idx >> 12) & 15;
    const int hh = idx >> 16;
    vt[((size_t)hh*144 + 128 + c16)*N_ + n] = (c16 == 0) ? (ushort)0x3F80 : (ushort)0;
  } else {                  // k1: g_src_b + gram_b
    float* eq   = smem;        // 48
    float* gs   = smem + 48;   // 768
    float* g2p  = smem + 816;  // 96
    float* part = smem + 912;  // 192
    const int i = b - 7432;
    if (t < 48) eq[t] = equ[(size_t)i*48 + t];
    __syncthreads();
    #pragma unroll
    for (int j = 0; j < 3; ++j) {
      float s = 0.f;
      #pragma unroll
      for (int m = 0; m < 16; ++m) s += eq[j*16+m] * W_equ[m*256 + t];
      s *= SQRT_E;
      gs[j*256 + t] = s;
      g_src_b[((size_t)i*3 + j)*256 + t] = f2bf(s);
    }
    __syncthreads();
    if (t < 192) {            // 2-way K-split of the gproj GEMV
      const int o = t % 96, half = t / 96;
      const int j = o >> 5, a = o & 31;
      const int e0 = half * 128;
      float s = 0.f;
      for (int e = 0; e < 128; ++e)
        s += gs[j*256 + e0 + e] * W_gproj[(size_t)(e0+e)*32 + a];
      part[t] = s;
    }
    __syncthreads();
    if (t < 96) g2p[t] = part[t] + part[96 + t];
    __syncthreads();
    #pragma unroll
    for (int r = 0; r < 4; ++r) {
      const int idx = r*256 + t;
      const int a = idx >> 5, bb = idx & 31;
      const float s = g2p[a]*g2p[bb] + g2p[32+a]*g2p[32+bb] + g2p[64+a]*g2p[64+bb];
      gram_b[(size_t)i*1024 + idx] = f2bf(s);
    }
  }
}

// ---------------- GEMM cores: BK=64, double-pumped, register prefetch -----------
template<int KTOT>
__device__ __forceinline__ void gemm_core(
    const ushort* __restrict__ A, const ushort* __restrict__ Bt,
    int bM, int bN, floatx4 acc[4], ushort* As, ushort* Bs)
{
  const int t = threadIdx.x;
  const int wave = t >> 6, lane = t & 63, quad = lane >> 4, m = lane & 15;
  #pragma unroll
  for (int ct = 0; ct < 4; ++ct) acc[ct] = {0.f, 0.f, 0.f, 0.f};
  const int ca = t*2, cb = t*2 + 1;
  const int ra = ca >> 3, pa = ca & 7;
  const int rb = cb >> 3, pb = cb & 7;
  const ushort* pA0 = A  + (size_t)(bM+ra)*KTOT + pa*8;
  const ushort* pA1 = A  + (size_t)(bM+rb)*KTOT + pb*8;
  const ushort* pB0 = Bt + (size_t)(bN+ra)*KTOT + pa*8;
  const ushort* pB1 = Bt + (size_t)(bN+rb)*KTOT + pb*8;
  short8 rA0 = *(const short8*)pA0, rA1 = *(const short8*)pA1;
  short8 rB0 = *(const short8*)pB0, rB1 = *(const short8*)pB1;
  for (int k0 = 0; k0 < KTOT; k0 += 64) {
    __syncthreads();
    *(short8*)&As[ra*72 + pa*8] = rA0;
    *(short8*)&As[rb*72 + pb*8] = rA1;
    *(short8*)&Bs[ra*72 + pa*8] = rB0;
    *(short8*)&Bs[rb*72 + pb*8] = rB1;
    if (k0 + 64 < KTOT) {
      pA0 += 64; pA1 += 64; pB0 += 64; pB1 += 64;
      rA0 = *(const short8*)pA0; rA1 = *(const short8*)pA1;
      rB0 = *(const short8*)pB0; rB1 = *(const short8*)pB1;
    }
    __syncthreads();
    #pragma unroll
    for (int ks = 0; ks < 2; ++ks) {
      const short8 af = *(const short8*)&As[(wave*16 + m)*72 + ks*32 + quad*8];
      #pragma unroll
      for (int ct = 0; ct < 4; ++ct) {
        const short8 bf = *(const short8*)&Bs[(ct*16 + m)*72 + ks*32 + quad*8];
        acc[ct] = __builtin_amdgcn_mfma_f32_16x16x32_bf16(af, bf, acc[ct], 0, 0, 0);
      }
    }
  }
}

template<int KTOT>
__device__ __forceinline__ void gemm_core3(
    const ushort* __restrict__ Ah, const ushort* __restrict__ Al,
    const ushort* __restrict__ Bth, const ushort* __restrict__ Btl,
    int bM, int bN, floatx4 acc[4],
    ushort* Ash, ushort* Asl, ushort* Bsh, ushort* Bsl)
{
  const int t = threadIdx.x;
  const int wave = t >> 6, lane = t & 63, quad = lane >> 4, m = lane & 15;
  #pragma unroll
  for (int ct = 0; ct < 4; ++ct) acc[ct] = {0.f, 0.f, 0.f, 0.f};
  const int ca = t*2, cb = t*2 + 1;
  const int ra = ca >> 3, pa = ca & 7;
  const int rb = cb >> 3, pb = cb & 7;
  const ushort* pAh0 = Ah  + (size_t)(bM+ra)*KTOT + pa*8;
  const ushort* pAh1 = Ah  + (size_t)(bM+rb)*KTOT + pb*8;
  const ushort* pAl0 = Al  + (size_t)(bM+ra)*KTOT + pa*8;
  const ushort* pAl1 = Al  + (size_t)(bM+rb)*KTOT + pb*8;
  const ushort* pBh0 = Bth + (size_t)(bN+ra)*KTOT + pa*8;
  const ushort* pBh1 = Bth + (size_t)(bN+rb)*KTOT + pb*8;
  const ushort* pBl0 = Btl + (size_t)(bN+ra)*KTOT + pa*8;
  const ushort* pBl1 = Btl + (size_t)(bN+rb)*KTOT + pb*8;
  short8 rAh0 = *(const short8*)pAh0, rAh1 = *(const short8*)pAh1;
  short8 rAl0 = *(const short8*)pAl0, rAl1 = *(const short8*)pAl1;
  short8 rBh0 = *(const short8*)pBh0, rBh1 = *(const short8*)pBh1;
  short8 rBl0 = *(const short8*)pBl0, rBl1 = *(const short8*)pBl1;
  for (int k0 = 0; k0 < KTOT; k0 += 64) {
    __syncthreads();
    *(short8*)&Ash[ra*72 + pa*8] = rAh0;
    *(short8*)&Ash[rb*72 + pb*8] = rAh1;
    *(short8*)&Asl[ra*72 + pa*8] = rAl0;
    *(short8*)&Asl[rb*72 + pb*8] = rAl1;
    *(short8*)&Bsh[ra*72 + pa*8] = rBh0;
    *(short8*)&Bsh[rb*72 + pb*8] = rBh1;
    *(short8*)&Bsl[ra*72 + pa*8] = rBl0;
    *(short8*)&Bsl[rb*72 + pb*8] = rBl1;
    if (k0 + 64 < KTOT) {
      pAh0 += 64; pAh1 += 64; pAl0 += 64; pAl1 += 64;
      pBh0 += 64; pBh1 += 64; pBl0 += 64; pBl1 += 64;
      rAh0 = *(const short8*)pAh0; rAh1 = *(const short8*)pAh1;
      rAl0 = *(const short8*)pAl0; rAl1 = *(const short8*)pAl1;
      rBh0 = *(const short8*)pBh0; rBh1 = *(const short8*)pBh1;
      rBl0 = *(const short8*)pBl0; rBl1 = *(const short8*)pBl1;
    }
    __syncthreads();
    #pragma unroll
    for (int ks = 0; ks < 2; ++ks) {
      const short8 ah = *(const short8*)&Ash[(wave*16 + m)*72 + ks*32 + quad*8];
      const short8 al = *(const short8*)&Asl[(wave*16 + m)*72 + ks*32 + quad*8];
      #pragma unroll
      for (int ct = 0; ct < 4; ++ct) {
        const short8 bh = *(const short8*)&Bsh[(ct*16 + m)*72 + ks*32 + quad*8];
        const short8 bl = *(const short8*)&Bsl[(ct*16 + m)*72 + ks*32 + quad*8];
        acc[ct] = __builtin_amdgcn_mfma_f32_16x16x32_bf16(ah, bl, acc[ct], 0, 0, 0);
        acc[ct] = __builtin_amdgcn_mfma_f32_16x16x32_bf16(al, bh, acc[ct], 0, 0, 0);
        acc[ct] = __builtin_amdgcn_mfma_f32_16x16x32_bf16(ah, bh, acc[ct], 0, 0, 0);
      }
    }
  }
}

// G1: hidden = relu(gram @ W_g1 + b_g1)
__global__ __launch_bounds__(256) void k_g1(
    const ushort* __restrict__ gram_b, const ushort* __restrict__ Wg1t,
    const float* __restrict__ b_g1, ushort* __restrict__ hidden)
{
  __shared__ __align__(16) ushort As[64*72], Bs[64*72];
  floatx4 acc[4];
  const int bM = blockIdx.x*64, bN = blockIdx.y*64;
  gemm_core<1024>(gram_b, Wg1t, bM, bN, acc, As, Bs);
  const int lane = threadIdx.x & 63, wave = threadIdx.x >> 6;
  const int quad = lane >> 4, m = lane & 15;
  #pragma unroll
  for (int ct = 0; ct < 4; ++ct) {
    const int c = bN + ct*16 + m;
    #pragma unroll
    for (int r = 0; r < 4; ++r) {
      const int i = bM + wave*16 + quad*4 + r;
      hidden[(size_t)i*512 + c] = f2bf(fmaxf(acc[ct][r] + b_g1[c], 0.f));
    }
  }
}

// G2: g2 = hidden @ W_g2 + b_g2 -> hi/lo into h2 cols 0..255
__global__ __launch_bounds__(256) void k_g2(
    const ushort* __restrict__ hidden, const ushort* __restrict__ Wg2t,
    const float* __restrict__ b_g2, ushort* __restrict__ h2h, ushort* __restrict__ h2l)
{
  __shared__ __align__(16) ushort As[64*72], Bs[64*72];
  floatx4 acc[4];
  const int bM = blockIdx.x*64, bN = blockIdx.y*64;
  gemm_core<512>(hidden, Wg2t, bM, bN, acc, As, Bs);
  const int lane = threadIdx.x & 63, wave = threadIdx.x >> 6;
  const int quad = lane >> 4, m = lane & 15;
  #pragma unroll
  for (int ct = 0; ct < 4; ++ct) {
    const int c = bN + ct*16 + m;
    #pragma unroll
    for (int r = 0; r < 4; ++r) {
      const int i = bM + wave*16 + quad*4 + r;
      const float s = acc[ct][r] + b_g2[c];
      const ushort hi = f2bf(s);
      h2h[(size_t)i*512 + c] = hi;
      h2l[(size_t)i*512 + c] = f2bf(s - bf2f(hi));
    }
  }
}

// G3+G4 fused: q/k hi/lo 3-term (k rounded to single bf16 at output);
// v 1-term; vg 1-term
__global__ __launch_bounds__(256) void k_g34(
    const ushort* __restrict__ h2h, const ushort* __restrict__ h2l,
    const ushort* __restrict__ Wth, const ushort* __restrict__ Wtl,
    const float* __restrict__ b_q, const float* __restrict__ b_k,
    const float* __restrict__ b_v,
    const ushort* __restrict__ g_src_b, const ushort* __restrict__ Wvgt,
    float* __restrict__ q_ws, ushort* __restrict__ kh,
    ushort* __restrict__ vt)
{
  __shared__ __align__(16) ushort S0[64*72], S1[64*72], S2[64*72], S3[64*72];
  const int lb = blockIdx.y*192 + blockIdx.x;     // grid (192,8) = 1536
  const int lane = threadIdx.x & 63, wave = threadIdx.x >> 6;
  const int quad = lane >> 4, m = lane & 15;
  floatx4 acc[4];
  if (lb < 768) {
    const int bM = (lb & 63)*64, bN = (lb >> 6)*64;
    if (bN < 512) {
      gemm_core3<512>(h2h, h2l, Wth, Wtl, bM, bN, acc, S0, S1, S2, S3);
      #pragma unroll
      for (int ct = 0; ct < 4; ++ct) {
        const int c = bN + ct*16 + m;
        #pragma unroll
        for (int r = 0; r < 4; ++r) {
          const int i = bM + wave*16 + quad*4 + r;
          if (c < 256) {
            const float s = acc[ct][r] + b_q[c];
            q_ws[((size_t)(c >> 5)*N_ + i)*32 + (c & 31)] = s * QSCALE;
          } else {
            const int cc = c - 256;
            const float s = acc[ct][r] + b_k[cc];
            kh[((size_t)(cc >> 5)*N_ + i)*32 + (cc & 31)] = f2bf(s);
          }
        }
      }
    } else {
      gemm_core<512>(h2h, Wth, bM, bN, acc, S0, S1);
      #pragma unroll
      for (int ct = 0; ct < 4; ++ct) {
        const int cc = bN + ct*16 + m - 512;
        #pragma unroll
        for (int r = 0; r < 4; ++r) {
          const int i = bM + wave*16 + quad*4 + r;
          const float s = acc[ct][r] + b_v[cc];
          vt[((size_t)(cc >> 5)*144 + (cc & 31))*N_ + i] = f2bf(s);
        }
      }
    }
  } else {
    const int lb2 = lb - 768;
    const int bM = (lb2 >> 2)*64, bN = (lb2 & 3)*64;
    gemm_core<256>(g_src_b, Wvgt, bM, bN, acc, S0, S1);
    #pragma unroll
    for (int ct = 0; ct < 4; ++ct) {
      const int c = bN + ct*16 + m;
      const int hh = c >> 5, d = c & 31;
      #pragma unroll
      for (int r = 0; r < 4; ++r) {
        const int i3 = bM + wave*16 + quad*4 + r;
        const int i = i3 / 3, j = i3 - 3*i;
        vt[((size_t)hh*144 + 32 + j*32 + d)*N_ + i] = f2bf(acc[ct][r]);
      }
    }
  }
}

// ---------------- K3: MFMA flash attention (TK=64, single-bf16 K) ---------------
// Split-K x3, register-prefetch, ones-col denominator, deferred rescale,
// DPP max, truncated-bf16 P, exp2-domain softmax. Q stays hi/lo (2-term MFMA);
// K is plain bf16 (logit err ~0.08 exp2-units, safe vs near-one-hot softmax).
__global__ __launch_bounds__(256, 4) void k3_attn(
    const float* __restrict__ q_ws, const ushort* __restrict__ kh,
    const ushort* __restrict__ vt,
    ushort* __restrict__ Po0, ushort* __restrict__ Po1, ushort* __restrict__ Po2,
    float* __restrict__ Pml)
{
  __shared__ __align__(16) ushort Khs[64*40];              // 5 KiB
  __shared__ __align__(16) ushort Vs[144*64];              // 18 KiB swizzled
  __shared__ __align__(16) ushort Pl[4*16*72];             // 9 KiB
  __shared__ float li_s[64];

  const int t    = threadIdx.x;
  const int wave = t >> 6;
  const int lane = t & 63;
  const int quad = lane >> 4;
  const int m    = lane & 15;
  const int h    = blockIdx.y;
  const int s    = blockIdx.z;
  const int n0q  = blockIdx.x * 64;

  const int ktb = (s == 0) ? 0  : (s == 1 ? 22 : 43);
  const int kte = (s == 0) ? 22 : (s == 1 ? 43 : 64);

  union { short8 v; ushort u[8]; } Aqh, Aql;
  {
    const float* qp = q_ws + ((size_t)h*N_ + n0q + wave*16 + m)*32 + quad*8;
    #pragma unroll
    for (int jj = 0; jj < 8; ++jj) {
      const float x = qp[jj];
      const ushort hi = f2bf(x);
      Aqh.u[jj] = hi;
      Aql.u[jj] = f2bf(x - bf2f(hi));
    }
  }

  floatx4 Of[9];
  #pragma unroll
  for (int nt = 0; nt < 9; ++nt) Of[nt] = {0.f, 0.f, 0.f, 0.f};
  float mi[4];
  #pragma unroll
  for (int r = 0; r < 4; ++r) mi[r] = -3.0e38f;

  const int krow = t >> 2, kch = (t & 3) * 8;

  const ushort* pKh = kh + ((size_t)h*N_ + ktb*64 + krow)*32 + kch;
  const ushort* pV[4];
  int wV[4];
  #pragma unroll
  for (int p = 0; p < 4; ++p) {
    const int idx = p*256 + t, row = idx >> 3, g = idx & 7;
    pV[p] = vt + ((size_t)h*144 + row)*N_ + ktb*64 + g*8;
    wV[p] = (row*8 + (g ^ (row & 7)))*8;
  }
  const ushort* pV4 = nullptr;
  int wV4 = 0;
  if (t < 128) {
    const int idx = 1024 + t, row = idx >> 3, g = idx & 7;
    pV4 = vt + ((size_t)h*144 + row)*N_ + ktb*64 + g*8;
    wV4 = (row*8 + (g ^ (row & 7)))*8;
  }

  short8 rK0 = *(const short8*)pKh;
  short8 rV[4], rV4e;
  #pragma unroll
  for (int p = 0; p < 4; ++p) rV[p] = *(const short8*)pV[p];
  if (t < 128) rV4e = *(const short8*)pV4;

  for (int kt = ktb; kt < kte; ++kt) {
    __syncthreads();
    *(short8*)&Khs[krow*40 + kch] = rK0;
    #pragma unroll
    for (int p = 0; p < 4; ++p) *(short8*)&Vs[wV[p]] = rV[p];
    if (t < 128) *(short8*)&Vs[wV4] = rV4e;
    if (kt + 1 < kte) {
      pKh += 2048;
      rK0 = *(const short8*)pKh;
      #pragma unroll
      for (int p = 0; p < 4; ++p) { pV[p] += 64; rV[p] = *(const short8*)pV[p]; }
      if (t < 128) { pV4 += 64; rV4e = *(const short8*)pV4; }
    }
    __syncthreads();

    // S = Q K^T (2-term: Q hi/lo x K bf16)
    floatx4 sf[4];
    #pragma unroll
    for (int kb = 0; kb < 4; ++kb) {
      const short8 bkh = *(const short8*)&Khs[(kb*16 + m)*40 + quad*8];
      floatx4 sv = {0.f, 0.f, 0.f, 0.f};
      sv = __builtin_amdgcn_mfma_f32_16x16x32_bf16(Aql.v, bkh, sv, 0, 0, 0);
      sv = __builtin_amdgcn_mfma_f32_16x16x32_bf16(Aqh.v, bkh, sv, 0, 0, 0);
      sf[kb] = sv;
    }

    float tm[4];
    bool need = false;
    #pragma unroll
    for (int r = 0; r < 4; ++r) {
      float nm = fmaxf(fmaxf(sf[0][r], sf[1][r]), fmaxf(sf[2][r], sf[3][r]));
      tm[r] = dpp_max16(nm);
      need |= (tm[r] > mi[r] + 20.f);
    }
    if (__any(need)) {
      #pragma unroll
      for (int r = 0; r < 4; ++r) {
        const float mn = fmaxf(mi[r], tm[r]);
        const float al = exp2f(mi[r] - mn);
        mi[r] = mn;
        #pragma unroll
        for (int nt = 0; nt < 9; ++nt) Of[nt][r] *= al;
      }
    }
    #pragma unroll
    for (int kb = 0; kb < 4; ++kb)
      #pragma unroll
      for (int r = 0; r < 4; ++r) {
        const float pv = exp2f(sf[kb][r] - mi[r]);
        Pl[wave*1152 + (quad*4 + r)*72 + kb*16 + m] =
            (ushort)(__float_as_uint(pv) >> 16);
      }

    #pragma unroll
    for (int ks = 0; ks < 2; ++ks) {
      const short8 ap = *(const short8*)&Pl[wave*1152 + m*72 + ks*32 + quad*8];
      #pragma unroll
      for (int nt = 0; nt < 9; ++nt) {
        const int row = nt*16 + m;
        const int pos = (ks*4 + quad) ^ (row & 7);
        const short8 bv = *(const short8*)&Vs[(row*8 + pos)*8];
        Of[nt] = __builtin_amdgcn_mfma_f32_16x16x32_bf16(ap, bv, Of[nt], 0, 0, 0);
      }
    }
  }

  if (m == 0) {
    #pragma unroll
    for (int r = 0; r < 4; ++r) li_s[wave*16 + quad*4 + r] = Of[8][r];
  }
  __syncthreads();
  const floatx4 liv = *(const floatx4*)&li_s[wave*16 + quad*4];
  float linv[4];
  #pragma unroll
  for (int r = 0; r < 4; ++r) linv[r] = 1.0f / liv[r];

  ushort* Po = (s == 0) ? Po0 : ((s == 1) ? Po1 : Po2);
  #pragma unroll
  for (int nt = 0; nt < 8; ++nt) {
    #pragma unroll
    for (int r = 0; r < 4; ++r) {
      const int n = n0q + wave*16 + quad*4 + r;
      Po[((size_t)h*N_ + n)*128 + nt*16 + m] = f2bf(Of[nt][r] * linv[r]);
    }
  }
  if (m == 0) {
    #pragma unroll
    for (int r = 0; r < 4; ++r) {
      const int n = n0q + wave*16 + quad*4 + r;
      Pml[(((size_t)s*8 + h)*N_ + n)*2 + 0] = mi[r];
      Pml[(((size_t)s*8 + h)*N_ + n)*2 + 1] = Of[8][r];
    }
  }
}

// ---------------- merge: combine 3 split-K partials (8 elems/thread) ------------
__global__ __launch_bounds__(256) void k_merge(
    const ushort* __restrict__ Po0, const ushort* __restrict__ Po1,
    const ushort* __restrict__ Po2, const float* __restrict__ Pml,
    ushort* __restrict__ out_v_b, ushort* __restrict__ out_g_b)
{
  const int idx = blockIdx.x*256 + threadIdx.x;
  const int c0 = (idx & 15) * 8;
  const int n  = (idx >> 4) & 4095;
  const int h  = idx >> 16;
  const float m1 = Pml[(((size_t)0*8 + h)*N_ + n)*2 + 0];
  const float l1 = Pml[(((size_t)0*8 + h)*N_ + n)*2 + 1];
  const float m2 = Pml[(((size_t)1*8 + h)*N_ + n)*2 + 0];
  const float l2 = Pml[(((size_t)1*8 + h)*N_ + n)*2 + 1];
  const float m3 = Pml[(((size_t)2*8 + h)*N_ + n)*2 + 0];
  const float l3 = Pml[(((size_t)2*8 + h)*N_ + n)*2 + 1];
  const float M = fmaxf(fmaxf(m1, m2), m3);
  const float w1 = exp2f(m1 - M) * l1;
  const float w2 = exp2f(m2 - M) * l2;
  const float w3 = exp2f(m3 - M) * l3;
  const float inv = 1.0f / (w1 + w2 + w3);
  union { short8 v; ushort u[8]; } a, b, c, res;
  a.v = *(const short8*)&Po0[((size_t)h*N_ + n)*128 + c0];
  b.v = *(const short8*)&Po1[((size_t)h*N_ + n)*128 + c0];
  c.v = *(const short8*)&Po2[((size_t)h*N_ + n)*128 + c0];
  #pragma unroll
  for (int j = 0; j < 8; ++j)
    res.u[j] = f2bf((w1*bf2f(a.u[j]) + w2*bf2f(b.u[j]) + w3*bf2f(c.u[j])) * inv);
  if (c0 < 32) {
    *(short8*)&out_v_b[(size_t)n*256 + h*32 + c0] = res.v;
  } else {
    const int j = (c0 - 32) >> 5, cc = (c0 - 32) & 31;
    *(short8*)&out_g_b[((size_t)n*3 + j)*256 + h*32 + cc] = res.v;
  }
}

// ---------------- k5a+k5b fused ----------------
__global__ __launch_bounds__(256) void k56ab(
    const ushort* __restrict__ out_v_b, const ushort* __restrict__ Wngt,
    const float* __restrict__ b_ng, const float* __restrict__ h,
    ushort* __restrict__ tmp_b,
    const ushort* __restrict__ out_g_b, const ushort* __restrict__ Wgoutt,
    const ushort* __restrict__ g_src_b, ushort* __restrict__ gsum_b)
{
  __shared__ __align__(16) ushort As[64*72], Bs[64*72];
  floatx4 acc[4];
  const int lane = threadIdx.x & 63, wave = threadIdx.x >> 6;
  const int quad = lane >> 4, m = lane & 15;
  const int bN = blockIdx.y*64;
  if (blockIdx.x < 64) {
    const int bM = blockIdx.x*64;
    gemm_core<256>(out_v_b, Wngt, bM, bN, acc, As, Bs);
    #pragma unroll
    for (int ct = 0; ct < 4; ++ct) {
      const int c = bN + ct*16 + m;
      #pragma unroll
      for (int r = 0; r < 4; ++r) {
        const int i = bM + wave*16 + quad*4 + r;
        tmp_b[(size_t)i*256 + c] =
            f2bf(acc[ct][r] + b_ng[c] + h[(size_t)i*256 + c] * SQRT_E);
      }
    }
  } else {
    const int bM = (blockIdx.x - 64)*64;
    gemm_core<256>(out_g_b, Wgoutt, bM, bN, acc, As, Bs);
    #pragma unroll
    for (int ct = 0; ct < 4; ++ct) {
      const int c = bN + ct*16 + m;
      #pragma unroll
      for (int r = 0; r < 4; ++r) {
        const int i = bM + wave*16 + quad*4 + r;
        gsum_b[(size_t)i*256 + c] =
            f2bf(acc[ct][r] + bf2f(g_src_b[(size_t)i*256 + c]));
      }
    }
  }
}

// ---------------- k5c+k5d fused ----------------
__global__ __launch_bounds__(256) void k56cd(
    const ushort* __restrict__ tmp_b, const ushort* __restrict__ Whdect,
    const float* __restrict__ b_hdec,
    const ushort* __restrict__ gsum_b, const ushort* __restrict__ Wgdect,
    float* __restrict__ out)
{
  __shared__ __align__(16) ushort As[64*72], Bs[64*72];
  const int t = threadIdx.x;
  const int lane = t & 63, wave = t >> 6;
  const int quad = lane >> 4, m = lane & 15;
  if (blockIdx.x < 64) {
    floatx4 acc[4];
    const int bM = blockIdx.x*64, bN = blockIdx.y*64;
    gemm_core<256>(tmp_b, Whdect, bM, bN, acc, As, Bs);
    #pragma unroll
    for (int ct = 0; ct < 4; ++ct) {
      const int c = bN + ct*16 + m;
      #pragma unroll
      for (int r = 0; r < 4; ++r) {
        const int i = bM + wave*16 + quad*4 + r;
        out[196608 + (size_t)i*256 + c] = acc[ct][r] + b_hdec[c];
      }
    }
  } else if (blockIdx.y == 0) {
    const int bM = (blockIdx.x - 64)*64;
    floatx4 acc = {0.f, 0.f, 0.f, 0.f};
    const int row = t >> 2, kq = (t & 3) * 8;
    for (int k0 = 0; k0 < 256; k0 += 32) {
      __syncthreads();
      *(short8*)&As[row*40 + kq] = *(const short8*)&gsum_b[(size_t)(bM+row)*256 + k0 + kq];
      if (t < 64)
        *(short8*)&Bs[(t>>2)*40 + kq] = *(const short8*)&Wgdect[(size_t)(t>>2)*256 + k0 + kq];
      __syncthreads();
      const short8 af = *(const short8*)&As[(wave*16 + m)*40 + quad*8];
      const short8 bf = *(const short8*)&Bs[m*40 + quad*8];
      acc = __builtin_amdgcn_mfma_f32_16x16x32_bf16(af, bf, acc, 0, 0, 0);
    }
    #pragma unroll
    for (int r = 0; r < 4; ++r)
      out[(size_t)(bM + wave*16 + quad*4 + r)*16 + m] = acc[r];
  }
}

extern "C" void kernel_launch(void* const* d_in, const int* in_sizes, int n_in,
                              void* d_out, int out_size, void* d_ws, size_t ws_size,
                              hipStream_t stream) {
  const float* equ    = (const float*)d_in[0];
  const float* h      = (const float*)d_in[1];
  const float* W_equ  = (const float*)d_in[4];
  const float* W_gproj= (const float*)d_in[5];
  const float* W_vg   = (const float*)d_in[6];
  const float* W_g1   = (const float*)d_in[7];
  const float* b_g1   = (const float*)d_in[8];
  const float* W_g2   = (const float*)d_in[9];
  const float* b_g2   = (const float*)d_in[10];
  const float* W_q    = (const float*)d_in[11];
  const float* b_q    = (const float*)d_in[12];
  const float* W_k    = (const float*)d_in[13];
  const float* b_k    = (const float*)d_in[14];
  const float* W_v    = (const float*)d_in[15];
  const float* b_v    = (const float*)d_in[16];
  const float* W_ng   = (const float*)d_in[17];
  const float* b_ng   = (const float*)d_in[18];
  const float* W_gout = (const float*)d_in[19];
  const float* W_gdec = (const float*)d_in[20];
  const float* W_hdec = (const float*)d_in[21];
  const float* b_hdec = (const float*)d_in[22];
  float* out = (float*)d_out;

  // ---- workspace layout (lifetimes annotated), peak 51.25 MiB (52 proven) ----
  char* wsb = (char*)d_ws;
  constexpr size_t MiB = 1048576;
  float*  q_ws    = (float*) (wsb +  0*MiB);            // 4 MiB [g34 -> k3]
  ushort* kh      = (ushort*)(wsb +  4*MiB);            // 2 MiB [g34 -> k3]
  ushort* vt      = (ushort*)(wsb +  8*MiB);            // 9 MiB [prep/g34 -> k3]
  ushort* h2h     = (ushort*)(wsb + 17*MiB);            // 4 MiB [prep/g2 -> g34]
  ushort* h2l     = (ushort*)(wsb + 21*MiB);            // 4 MiB
  ushort* g_src_b = (ushort*)(wsb + 25*MiB);            // 6 MiB [prep -> g34,k56ab]
  ushort* wbase   = (ushort*)(wsb + 31*MiB);            // 2.875 MiB [prep -> g34]
  ushort* Wg1t = wbase;                                 // 512x1024
  ushort* Wg2t = wbase + 524288;                        // 256x512
  ushort* Wth  = wbase + 655360;                        // 768x512 hi
  ushort* Wtl  = wbase + 1048576;                       // 768x512 lo
  ushort* Wvgt = wbase + 1441792;                       // 256x256
  ushort* wbase2  = (ushort*)(wsb + 34*MiB);            // 0.4 MiB [prep -> k56*]
  ushort* Wngt   = wbase2;                              // 256x256
  ushort* Wgoutt = wbase2 + 65536;                      // 256x256
  ushort* Whdect = wbase2 + 131072;                     // 256x256
  ushort* Wgdect = wbase2 + 196608;                     // 16x256
  ushort* gram_b  = (ushort*)(wsb + 34*MiB + 524288);   // 8 MiB [prep -> g1]
  ushort* hidden  = (ushort*)(wsb + 42*MiB + 524288);   // 4 MiB [g1 -> g2]
  // split-K x3 attention partials (all alias dead regions):
  ushort* Po0     = (ushort*)(wsb + 17*MiB);            // 8 MiB [k3 -> merge] alias h2h/h2l
  ushort* Po1     = (ushort*)(wsb + 34*MiB + 524288);   // 8 MiB [k3 -> merge] alias gram_b
  ushort* Po2     = (ushort*)(wsb + 42*MiB + 524288);   // 8 MiB [k3 -> merge] alias hidden+
  float*  Pml     = (float*) (wsb + 50*MiB + 524288);   // 0.75 MiB [k3 -> merge]
  ushort* out_v_b = (ushort*)(wsb +  4*MiB);            // 2 MiB [merge -> k56ab] alias kh
  ushort* out_g_b = (ushort*)(wsb +  8*MiB);            // 6 MiB [merge -> k56ab] alias vt
  ushort* tmp_b   = (ushort*)(wsb + 42*MiB + 524288);   // 2 MiB [k56ab -> k56cd] alias Po2
  ushort* gsum_b  = (ushort*)(wsb + 34*MiB + 524288);   // 6 MiB [k56ab -> k56cd] alias Po1

  // ---- 1 mega-prep launch (10 transposes + hsplit + vinit + k1) ----
  k_prep<<<11528, 256, 0, stream>>>(
      equ, h, W_equ, W_gproj, W_g1, W_g2, W_q, W_k, W_v,
      W_vg, W_ng, W_gout, W_hdec, W_gdec,
      Wg1t, Wg2t, Wth, Wtl, Wvgt, Wngt, Wgoutt, Whdect, Wgdect,
      h2h, h2l, vt, g_src_b, gram_b);

  // ---- GEMM chain (BK=64 double-pumped cores) ----
  k_g1<<<dim3(64, 8), 256, 0, stream>>>(gram_b, Wg1t, b_g1, hidden);
  k_g2<<<dim3(64, 4), 256, 0, stream>>>(hidden, Wg2t, b_g2, h2h, h2l);
  k_g34<<<dim3(192, 8), 256, 0, stream>>>(h2h, h2l, Wth, Wtl, b_q, b_k, b_v,
                                          g_src_b, Wvgt, q_ws, kh, vt);

  // ---- attention (TK=64, split-K x3, single-bf16 K) + merge ----
  dim3 g3(64, 8, 3);
  k3_attn<<<g3, 256, 0, stream>>>(q_ws, kh, vt, Po0, Po1, Po2, Pml);
  k_merge<<<2048, 256, 0, stream>>>(Po0, Po1, Po2, Pml, out_v_b, out_g_b);

  // ---- epilogue GEMMs (fused pairs) ----
  k56ab<<<dim3(256, 4), 256, 0, stream>>>(out_v_b, Wngt, b_ng, h, tmp_b,
                                          out_g_b, Wgoutt, g_src_b, gsum_b);
  k56cd<<<dim3(256, 4), 256, 0, stream>>>(tmp_b, Whdect, b_hdec,
                                          gsum_b, Wgdect, out);
}

// Round 15
// 274.660 us; speedup vs baseline: 1.2058x; 1.0356x over previous
//
#include <hip/hip_runtime.h>
#include <hip/hip_bf16.h>

typedef __attribute__((ext_vector_type(8))) short short8;
typedef __attribute__((ext_vector_type(4))) float floatx4;

constexpr int N_ = 4096;
constexpr float SQRT_E = 16.0f;
// q scale folded with log2(e): softmax computed in exp2 domain
constexpr float QSCALE = 0.17677669529663687f * 1.4426950408889634f;

__device__ __forceinline__ ushort f2bf(float x) {
  __hip_bfloat16 h = __float2bfloat16(x);
  return *reinterpret_cast<ushort*>(&h);
}
__device__ __forceinline__ float bf2f(ushort b) {
  unsigned int u = ((unsigned int)b) << 16;
  return __uint_as_float(u);
}

// all 16 lanes of each aligned 16-lane group get the group max (VALU DPP, not LDS)
__device__ __forceinline__ float dpp_max16(float x) {
  int v = __float_as_int(x);
  int y;
  y = __builtin_amdgcn_update_dpp(v, v, 0x128, 0xf, 0xf, false); // row_ror:8
  v = __float_as_int(fmaxf(__int_as_float(v), __int_as_float(y)));
  y = __builtin_amdgcn_update_dpp(v, v, 0x124, 0xf, 0xf, false); // row_ror:4
  v = __float_as_int(fmaxf(__int_as_float(v), __int_as_float(y)));
  y = __builtin_amdgcn_update_dpp(v, v, 0x122, 0xf, 0xf, false); // row_ror:2
  v = __float_as_int(fmaxf(__int_as_float(v), __int_as_float(y)));
  y = __builtin_amdgcn_update_dpp(v, v, 0x121, 0xf, 0xf, false); // row_ror:1
  v = __float_as_int(fmaxf(__int_as_float(v), __int_as_float(y)));
  return __int_as_float(v);
}

// ---------------- transpose helper (device side of mega-prep) ----------------
__device__ __forceinline__ void do_transpose(
    const float* __restrict__ src, ushort* __restrict__ dsth,
    ushort* __restrict__ dstl, int R, int C, int lb, int cb_shift,
    float* smem, int hasLo)
{
  float (*tile)[33] = (float(*)[33])smem;
  const int r0 = (lb >> cb_shift) * 32;
  const int c0 = (lb & ((1 << cb_shift) - 1)) * 32;
  const int tx = threadIdx.x & 31, ty = threadIdx.x >> 5;
  #pragma unroll
  for (int p = 0; p < 4; ++p) {
    const int lr = p*8 + ty;
    tile[lr][tx] = (r0+lr < R && c0+tx < C) ? src[(size_t)(r0+lr)*C + c0 + tx] : 0.f;
  }
  __syncthreads();
  #pragma unroll
  for (int p = 0; p < 4; ++p) {
    const int dc = p*8 + ty;
    if (c0+dc < C && r0+tx < R) {
      const float v = tile[tx][dc];
      const ushort hi = f2bf(v);
      dsth[(size_t)(c0+dc)*R + r0 + tx] = hi;
      if (hasLo) dstl[(size_t)(c0+dc)*R + r0 + tx] = f2bf(v - bf2f(hi));
    }
  }
}

// ---------------- mega-prep: all transposes + hsplit + vinit + k1 in ONE launch --
__global__ __launch_bounds__(256) void k_prep(
    const float* __restrict__ equ, const float* __restrict__ h,
    const float* __restrict__ W_equ, const float* __restrict__ W_gproj,
    const float* __restrict__ W_g1, const float* __restrict__ W_g2,
    const float* __restrict__ W_q, const float* __restrict__ W_k,
    const float* __restrict__ W_v, const float* __restrict__ W_vg,
    const float* __restrict__ W_ng, const float* __restrict__ W_gout,
    const float* __restrict__ W_hdec, const float* __restrict__ W_gdec,
    ushort* __restrict__ Wg1t, ushort* __restrict__ Wg2t,
    ushort* __restrict__ Wth, ushort* __restrict__ Wtl,
    ushort* __restrict__ Wvgt, ushort* __restrict__ Wngt,
    ushort* __restrict__ Wgoutt, ushort* __restrict__ Whdect,
    ushort* __restrict__ Wgdect,
    ushort* __restrict__ h2h, ushort* __restrict__ h2l,
    ushort* __restrict__ vt,
    ushort* __restrict__ g_src_b, ushort* __restrict__ gram_b)
{
  __shared__ __align__(16) float smem[1120];
  const int b = blockIdx.x;
  const int t = threadIdx.x;

  if (b < 512) {            // W_g1 [1024,512] -> Wg1t
    do_transpose(W_g1, Wg1t, nullptr, 1024, 512, b, 4, smem, 0);
  } else if (b < 640) {     // W_g2 [512,256]
    do_transpose(W_g2, Wg2t, nullptr, 512, 256, b-512, 3, smem, 0);
  } else if (b < 768) {     // W_q hi/lo
    do_transpose(W_q, Wth, Wtl, 512, 256, b-640, 3, smem, 1);
  } else if (b < 896) {     // W_k hi/lo
    do_transpose(W_k, Wth + 256*512, Wtl + 256*512, 512, 256, b-768, 3, smem, 1);
  } else if (b < 1024) {    // W_v hi/lo
    do_transpose(W_v, Wth + 512*512, Wtl + 512*512, 512, 256, b-896, 3, smem, 1);
  } else if (b < 1088) {    // W_vg
    do_transpose(W_vg, Wvgt, nullptr, 256, 256, b-1024, 3, smem, 0);
  } else if (b < 1152) {    // W_ng
    do_transpose(W_ng, Wngt, nullptr, 256, 256, b-1088, 3, smem, 0);
  } else if (b < 1216) {    // W_gout
    do_transpose(W_gout, Wgoutt, nullptr, 256, 256, b-1152, 3, smem, 0);
  } else if (b < 1280) {    // W_hdec
    do_transpose(W_hdec, Whdect, nullptr, 256, 256, b-1216, 3, smem, 0);
  } else if (b < 1288) {    // W_gdec [256,16]
    do_transpose(W_gdec, Wgdect, nullptr, 256, 16, b-1280, 0, smem, 0);
  } else if (b < 5384) {    // hsplit: h_src half of h2 (hi/lo)
    const int i = b - 1288;
    const float v = h[(size_t)i*256 + t] * SQRT_E;
    const ushort hi = f2bf(v);
    h2h[(size_t)i*512 + 256 + t] = hi;
    h2l[(size_t)i*512 + 256 + t] = f2bf(v - bf2f(hi));
  } else if (b < 7432) {    // vinit: ones-col + zero ext
    const int idx = (b - 5384)*256 + t;
    const int n = idx & 4095;
    const int c16 = (idx >> 12) & 15;
    const int hh = idx >> 16;
    vt[((size_t)hh*144 + 128 + c16)*N_ + n] = (c16 == 0) ? (ushort)0x3F80 : (ushort)0;
  } else {                  // k1: g_src_b + gram_b
    float* eq   = smem;        // 48
    float* gs   = smem + 48;   // 768
    float* g2p  = smem + 816;  // 96
    float* part = smem + 912;  // 192
    const int i = b - 7432;
    if (t < 48) eq[t] = equ[(size_t)i*48 + t];
    __syncthreads();
    #pragma unroll
    for (int j = 0; j < 3; ++j) {
      float s = 0.f;
      #pragma unroll
      for (int m = 0; m < 16; ++m) s += eq[j*16+m] * W_equ[m*256 + t];
      s *= SQRT_E;
      gs[j*256 + t] = s;
      g_src_b[((size_t)i*3 + j)*256 + t] = f2bf(s);
    }
    __syncthreads();
    if (t < 192) {            // 2-way K-split of the gproj GEMV
      const int o = t % 96, half = t / 96;
      const int j = o >> 5, a = o & 31;
      const int e0 = half * 128;
      float s = 0.f;
      for (int e = 0; e < 128; ++e)
        s += gs[j*256 + e0 + e] * W_gproj[(size_t)(e0+e)*32 + a];
      part[t] = s;
    }
    __syncthreads();
    if (t < 96) g2p[t] = part[t] + part[96 + t];
    __syncthreads();
    #pragma unroll
    for (int r = 0; r < 4; ++r) {
      const int idx = r*256 + t;
      const int a = idx >> 5, bb = idx & 31;
      const float s = g2p[a]*g2p[bb] + g2p[32+a]*g2p[32+bb] + g2p[64+a]*g2p[64+bb];
      gram_b[(size_t)i*1024 + idx] = f2bf(s);
    }
  }
}

// ---------------- GEMM cores: BK=64, double-pumped, register prefetch -----------
template<int KTOT>
__device__ __forceinline__ void gemm_core(
    const ushort* __restrict__ A, const ushort* __restrict__ Bt,
    int bM, int bN, floatx4 acc[4], ushort* As, ushort* Bs)
{
  const int t = threadIdx.x;
  const int wave = t >> 6, lane = t & 63, quad = lane >> 4, m = lane & 15;
  #pragma unroll
  for (int ct = 0; ct < 4; ++ct) acc[ct] = {0.f, 0.f, 0.f, 0.f};
  const int ca = t*2, cb = t*2 + 1;
  const int ra = ca >> 3, pa = ca & 7;
  const int rb = cb >> 3, pb = cb & 7;
  const ushort* pA0 = A  + (size_t)(bM+ra)*KTOT + pa*8;
  const ushort* pA1 = A  + (size_t)(bM+rb)*KTOT + pb*8;
  const ushort* pB0 = Bt + (size_t)(bN+ra)*KTOT + pa*8;
  const ushort* pB1 = Bt + (size_t)(bN+rb)*KTOT + pb*8;
  short8 rA0 = *(const short8*)pA0, rA1 = *(const short8*)pA1;
  short8 rB0 = *(const short8*)pB0, rB1 = *(const short8*)pB1;
  for (int k0 = 0; k0 < KTOT; k0 += 64) {
    __syncthreads();
    *(short8*)&As[ra*72 + pa*8] = rA0;
    *(short8*)&As[rb*72 + pb*8] = rA1;
    *(short8*)&Bs[ra*72 + pa*8] = rB0;
    *(short8*)&Bs[rb*72 + pb*8] = rB1;
    if (k0 + 64 < KTOT) {
      pA0 += 64; pA1 += 64; pB0 += 64; pB1 += 64;
      rA0 = *(const short8*)pA0; rA1 = *(const short8*)pA1;
      rB0 = *(const short8*)pB0; rB1 = *(const short8*)pB1;
    }
    __syncthreads();
    #pragma unroll
    for (int ks = 0; ks < 2; ++ks) {
      const short8 af = *(const short8*)&As[(wave*16 + m)*72 + ks*32 + quad*8];
      #pragma unroll
      for (int ct = 0; ct < 4; ++ct) {
        const short8 bf = *(const short8*)&Bs[(ct*16 + m)*72 + ks*32 + quad*8];
        acc[ct] = __builtin_amdgcn_mfma_f32_16x16x32_bf16(af, bf, acc[ct], 0, 0, 0);
      }
    }
  }
}

template<int KTOT>
__device__ __forceinline__ void gemm_core3(
    const ushort* __restrict__ Ah, const ushort* __restrict__ Al,
    const ushort* __restrict__ Bth, const ushort* __restrict__ Btl,
    int bM, int bN, floatx4 acc[4],
    ushort* Ash, ushort* Asl, ushort* Bsh, ushort* Bsl)
{
  const int t = threadIdx.x;
  const int wave = t >> 6, lane = t & 63, quad = lane >> 4, m = lane & 15;
  #pragma unroll
  for (int ct = 0; ct < 4; ++ct) acc[ct] = {0.f, 0.f, 0.f, 0.f};
  const int ca = t*2, cb = t*2 + 1;
  const int ra = ca >> 3, pa = ca & 7;
  const int rb = cb >> 3, pb = cb & 7;
  const ushort* pAh0 = Ah  + (size_t)(bM+ra)*KTOT + pa*8;
  const ushort* pAh1 = Ah  + (size_t)(bM+rb)*KTOT + pb*8;
  const ushort* pAl0 = Al  + (size_t)(bM+ra)*KTOT + pa*8;
  const ushort* pAl1 = Al  + (size_t)(bM+rb)*KTOT + pb*8;
  const ushort* pBh0 = Bth + (size_t)(bN+ra)*KTOT + pa*8;
  const ushort* pBh1 = Bth + (size_t)(bN+rb)*KTOT + pb*8;
  const ushort* pBl0 = Btl + (size_t)(bN+ra)*KTOT + pa*8;
  const ushort* pBl1 = Btl + (size_t)(bN+rb)*KTOT + pb*8;
  short8 rAh0 = *(const short8*)pAh0, rAh1 = *(const short8*)pAh1;
  short8 rAl0 = *(const short8*)pAl0, rAl1 = *(const short8*)pAl1;
  short8 rBh0 = *(const short8*)pBh0, rBh1 = *(const short8*)pBh1;
  short8 rBl0 = *(const short8*)pBl0, rBl1 = *(const short8*)pBl1;
  for (int k0 = 0; k0 < KTOT; k0 += 64) {
    __syncthreads();
    *(short8*)&Ash[ra*72 + pa*8] = rAh0;
    *(short8*)&Ash[rb*72 + pb*8] = rAh1;
    *(short8*)&Asl[ra*72 + pa*8] = rAl0;
    *(short8*)&Asl[rb*72 + pb*8] = rAl1;
    *(short8*)&Bsh[ra*72 + pa*8] = rBh0;
    *(short8*)&Bsh[rb*72 + pb*8] = rBh1;
    *(short8*)&Bsl[ra*72 + pa*8] = rBl0;
    *(short8*)&Bsl[rb*72 + pb*8] = rBl1;
    if (k0 + 64 < KTOT) {
      pAh0 += 64; pAh1 += 64; pAl0 += 64; pAl1 += 64;
      pBh0 += 64; pBh1 += 64; pBl0 += 64; pBl1 += 64;
      rAh0 = *(const short8*)pAh0; rAh1 = *(const short8*)pAh1;
      rAl0 = *(const short8*)pAl0; rAl1 = *(const short8*)pAl1;
      rBh0 = *(const short8*)pBh0; rBh1 = *(const short8*)pBh1;
      rBl0 = *(const short8*)pBl0; rBl1 = *(const short8*)pBl1;
    }
    __syncthreads();
    #pragma unroll
    for (int ks = 0; ks < 2; ++ks) {
      const short8 ah = *(const short8*)&Ash[(wave*16 + m)*72 + ks*32 + quad*8];
      const short8 al = *(const short8*)&Asl[(wave*16 + m)*72 + ks*32 + quad*8];
      #pragma unroll
      for (int ct = 0; ct < 4; ++ct) {
        const short8 bh = *(const short8*)&Bsh[(ct*16 + m)*72 + ks*32 + quad*8];
        const short8 bl = *(const short8*)&Bsl[(ct*16 + m)*72 + ks*32 + quad*8];
        acc[ct] = __builtin_amdgcn_mfma_f32_16x16x32_bf16(ah, bl, acc[ct], 0, 0, 0);
        acc[ct] = __builtin_amdgcn_mfma_f32_16x16x32_bf16(al, bh, acc[ct], 0, 0, 0);
        acc[ct] = __builtin_amdgcn_mfma_f32_16x16x32_bf16(ah, bh, acc[ct], 0, 0, 0);
      }
    }
  }
}

// G1: hidden = relu(gram @ W_g1 + b_g1)
__global__ __launch_bounds__(256) void k_g1(
    const ushort* __restrict__ gram_b, const ushort* __restrict__ Wg1t,
    const float* __restrict__ b_g1, ushort* __restrict__ hidden)
{
  __shared__ __align__(16) ushort As[64*72], Bs[64*72];
  floatx4 acc[4];
  const int bM = blockIdx.x*64, bN = blockIdx.y*64;
  gemm_core<1024>(gram_b, Wg1t, bM, bN, acc, As, Bs);
  const int lane = threadIdx.x & 63, wave = threadIdx.x >> 6;
  const int quad = lane >> 4, m = lane & 15;
  #pragma unroll
  for (int ct = 0; ct < 4; ++ct) {
    const int c = bN + ct*16 + m;
    #pragma unroll
    for (int r = 0; r < 4; ++r) {
      const int i = bM + wave*16 + quad*4 + r;
      hidden[(size_t)i*512 + c] = f2bf(fmaxf(acc[ct][r] + b_g1[c], 0.f));
    }
  }
}

// G2: g2 = hidden @ W_g2 + b_g2 -> hi/lo into h2 cols 0..255
__global__ __launch_bounds__(256) void k_g2(
    const ushort* __restrict__ hidden, const ushort* __restrict__ Wg2t,
    const float* __restrict__ b_g2, ushort* __restrict__ h2h, ushort* __restrict__ h2l)
{
  __shared__ __align__(16) ushort As[64*72], Bs[64*72];
  floatx4 acc[4];
  const int bM = blockIdx.x*64, bN = blockIdx.y*64;
  gemm_core<512>(hidden, Wg2t, bM, bN, acc, As, Bs);
  const int lane = threadIdx.x & 63, wave = threadIdx.x >> 6;
  const int quad = lane >> 4, m = lane & 15;
  #pragma unroll
  for (int ct = 0; ct < 4; ++ct) {
    const int c = bN + ct*16 + m;
    #pragma unroll
    for (int r = 0; r < 4; ++r) {
      const int i = bM + wave*16 + quad*4 + r;
      const float s = acc[ct][r] + b_g2[c];
      const ushort hi = f2bf(s);
      h2h[(size_t)i*512 + c] = hi;
      h2l[(size_t)i*512 + c] = f2bf(s - bf2f(hi));
    }
  }
}

// G3+G4 fused: q/k hi/lo 3-term (k rounded to single bf16 at output);
// v 1-term; vg 1-term
__global__ __launch_bounds__(256) void k_g34(
    const ushort* __restrict__ h2h, const ushort* __restrict__ h2l,
    const ushort* __restrict__ Wth, const ushort* __restrict__ Wtl,
    const float* __restrict__ b_q, const float* __restrict__ b_k,
    const float* __restrict__ b_v,
    const ushort* __restrict__ g_src_b, const ushort* __restrict__ Wvgt,
    float* __restrict__ q_ws, ushort* __restrict__ kh,
    ushort* __restrict__ vt)
{
  __shared__ __align__(16) ushort S0[64*72], S1[64*72], S2[64*72], S3[64*72];
  const int lb = blockIdx.y*192 + blockIdx.x;     // grid (192,8) = 1536
  const int lane = threadIdx.x & 63, wave = threadIdx.x >> 6;
  const int quad = lane >> 4, m = lane & 15;
  floatx4 acc[4];
  if (lb < 768) {
    const int bM = (lb & 63)*64, bN = (lb >> 6)*64;
    if (bN < 512) {
      gemm_core3<512>(h2h, h2l, Wth, Wtl, bM, bN, acc, S0, S1, S2, S3);
      #pragma unroll
      for (int ct = 0; ct < 4; ++ct) {
        const int c = bN + ct*16 + m;
        #pragma unroll
        for (int r = 0; r < 4; ++r) {
          const int i = bM + wave*16 + quad*4 + r;
          if (c < 256) {
            const float s = acc[ct][r] + b_q[c];
            q_ws[((size_t)(c >> 5)*N_ + i)*32 + (c & 31)] = s * QSCALE;
          } else {
            const int cc = c - 256;
            const float s = acc[ct][r] + b_k[cc];
            kh[((size_t)(cc >> 5)*N_ + i)*32 + (cc & 31)] = f2bf(s);
          }
        }
      }
    } else {
      gemm_core<512>(h2h, Wth, bM, bN, acc, S0, S1);
      #pragma unroll
      for (int ct = 0; ct < 4; ++ct) {
        const int cc = bN + ct*16 + m - 512;
        #pragma unroll
        for (int r = 0; r < 4; ++r) {
          const int i = bM + wave*16 + quad*4 + r;
          const float s = acc[ct][r] + b_v[cc];
          vt[((size_t)(cc >> 5)*144 + (cc & 31))*N_ + i] = f2bf(s);
        }
      }
    }
  } else {
    const int lb2 = lb - 768;
    const int bM = (lb2 >> 2)*64, bN = (lb2 & 3)*64;
    gemm_core<256>(g_src_b, Wvgt, bM, bN, acc, S0, S1);
    #pragma unroll
    for (int ct = 0; ct < 4; ++ct) {
      const int c = bN + ct*16 + m;
      const int hh = c >> 5, d = c & 31;
      #pragma unroll
      for (int r = 0; r < 4; ++r) {
        const int i3 = bM + wave*16 + quad*4 + r;
        const int i = i3 / 3, j = i3 - 3*i;
        vt[((size_t)hh*144 + 32 + j*32 + d)*N_ + i] = f2bf(acc[ct][r]);
      }
    }
  }
}

// ---------------- K3: MFMA flash attention (TK=64, single-bf16 K) ---------------
// Split-K x3, register-prefetch, ones-col denominator, deferred rescale,
// DPP max, exp2-domain softmax. P computed via Schraudolph int-exp2 fused to
// bf16 (3 full-rate VALU ops vs quarter-rate v_exp_f32; ~2-3% relative err,
// self-consistent with the ones-col denominator).
__global__ __launch_bounds__(256, 4) void k3_attn(
    const float* __restrict__ q_ws, const ushort* __restrict__ kh,
    const ushort* __restrict__ vt,
    ushort* __restrict__ Po0, ushort* __restrict__ Po1, ushort* __restrict__ Po2,
    float* __restrict__ Pml)
{
  __shared__ __align__(16) ushort Khs[64*40];              // 5 KiB
  __shared__ __align__(16) ushort Vs[144*64];              // 18 KiB swizzled
  __shared__ __align__(16) ushort Pl[4*16*72];             // 9 KiB
  __shared__ float li_s[64];

  const int t    = threadIdx.x;
  const int wave = t >> 6;
  const int lane = t & 63;
  const int quad = lane >> 4;
  const int m    = lane & 15;
  const int h    = blockIdx.y;
  const int s    = blockIdx.z;
  const int n0q  = blockIdx.x * 64;

  const int ktb = (s == 0) ? 0  : (s == 1 ? 22 : 43);
  const int kte = (s == 0) ? 22 : (s == 1 ? 43 : 64);

  union { short8 v; ushort u[8]; } Aqh, Aql;
  {
    const float* qp = q_ws + ((size_t)h*N_ + n0q + wave*16 + m)*32 + quad*8;
    #pragma unroll
    for (int jj = 0; jj < 8; ++jj) {
      const float x = qp[jj];
      const ushort hi = f2bf(x);
      Aqh.u[jj] = hi;
      Aql.u[jj] = f2bf(x - bf2f(hi));
    }
  }

  floatx4 Of[9];
  #pragma unroll
  for (int nt = 0; nt < 9; ++nt) Of[nt] = {0.f, 0.f, 0.f, 0.f};
  float mi[4];
  #pragma unroll
  for (int r = 0; r < 4; ++r) mi[r] = -3.0e38f;

  const int krow = t >> 2, kch = (t & 3) * 8;

  const ushort* pKh = kh + ((size_t)h*N_ + ktb*64 + krow)*32 + kch;
  const ushort* pV[4];
  int wV[4];
  #pragma unroll
  for (int p = 0; p < 4; ++p) {
    const int idx = p*256 + t, row = idx >> 3, g = idx & 7;
    pV[p] = vt + ((size_t)h*144 + row)*N_ + ktb*64 + g*8;
    wV[p] = (row*8 + (g ^ (row & 7)))*8;
  }
  const ushort* pV4 = nullptr;
  int wV4 = 0;
  if (t < 128) {
    const int idx = 1024 + t, row = idx >> 3, g = idx & 7;
    pV4 = vt + ((size_t)h*144 + row)*N_ + ktb*64 + g*8;
    wV4 = (row*8 + (g ^ (row & 7)))*8;
  }

  short8 rK0 = *(const short8*)pKh;
  short8 rV[4], rV4e;
  #pragma unroll
  for (int p = 0; p < 4; ++p) rV[p] = *(const short8*)pV[p];
  if (t < 128) rV4e = *(const short8*)pV4;

  for (int kt = ktb; kt < kte; ++kt) {
    __syncthreads();
    *(short8*)&Khs[krow*40 + kch] = rK0;
    #pragma unroll
    for (int p = 0; p < 4; ++p) *(short8*)&Vs[wV[p]] = rV[p];
    if (t < 128) *(short8*)&Vs[wV4] = rV4e;
    if (kt + 1 < kte) {
      pKh += 2048;
      rK0 = *(const short8*)pKh;
      #pragma unroll
      for (int p = 0; p < 4; ++p) { pV[p] += 64; rV[p] = *(const short8*)pV[p]; }
      if (t < 128) { pV4 += 64; rV4e = *(const short8*)pV4; }
    }
    __syncthreads();

    // S = Q K^T (2-term: Q hi/lo x K bf16)
    floatx4 sf[4];
    #pragma unroll
    for (int kb = 0; kb < 4; ++kb) {
      const short8 bkh = *(const short8*)&Khs[(kb*16 + m)*40 + quad*8];
      floatx4 sv = {0.f, 0.f, 0.f, 0.f};
      sv = __builtin_amdgcn_mfma_f32_16x16x32_bf16(Aql.v, bkh, sv, 0, 0, 0);
      sv = __builtin_amdgcn_mfma_f32_16x16x32_bf16(Aqh.v, bkh, sv, 0, 0, 0);
      sf[kb] = sv;
    }

    float tm[4];
    bool need = false;
    #pragma unroll
    for (int r = 0; r < 4; ++r) {
      float nm = fmaxf(fmaxf(sf[0][r], sf[1][r]), fmaxf(sf[2][r], sf[3][r]));
      tm[r] = dpp_max16(nm);
      need |= (tm[r] > mi[r] + 20.f);
    }
    if (__any(need)) {
      #pragma unroll
      for (int r = 0; r < 4; ++r) {
        const float mn = fmaxf(mi[r], tm[r]);
        const float al = exp2f(mi[r] - mn);   // precise: multiplies num+denom equally
        mi[r] = mn;
        #pragma unroll
        for (int nt = 0; nt < 9; ++nt) Of[nt][r] *= al;
      }
    }
    // P = exp2(S - mi) via Schraudolph int trick, fused to truncated bf16.
    // base = C - mi*2^23; P_bits = (int)(s*2^23 + base) >> 16. mi is finite here
    // (first tile forces the rescale branch); clamp guards the ~9-sigma underflow.
    float base[4];
    #pragma unroll
    for (int r = 0; r < 4; ++r) base[r] = 1064866805.0f - mi[r]*8388608.0f;
    #pragma unroll
    for (int kb = 0; kb < 4; ++kb)
      #pragma unroll
      for (int r = 0; r < 4; ++r) {
        int pi = (int)(sf[kb][r]*8388608.0f + base[r]);
        pi = pi < 0 ? 0 : pi;
        Pl[wave*1152 + (quad*4 + r)*72 + kb*16 + m] = (ushort)(pi >> 16);
      }

    #pragma unroll
    for (int ks = 0; ks < 2; ++ks) {
      const short8 ap = *(const short8*)&Pl[wave*1152 + m*72 + ks*32 + quad*8];
      #pragma unroll
      for (int nt = 0; nt < 9; ++nt) {
        const int row = nt*16 + m;
        const int pos = (ks*4 + quad) ^ (row & 7);
        const short8 bv = *(const short8*)&Vs[(row*8 + pos)*8];
        Of[nt] = __builtin_amdgcn_mfma_f32_16x16x32_bf16(ap, bv, Of[nt], 0, 0, 0);
      }
    }
  }

  if (m == 0) {
    #pragma unroll
    for (int r = 0; r < 4; ++r) li_s[wave*16 + quad*4 + r] = Of[8][r];
  }
  __syncthreads();
  const floatx4 liv = *(const floatx4*)&li_s[wave*16 + quad*4];
  float linv[4];
  #pragma unroll
  for (int r = 0; r < 4; ++r) linv[r] = 1.0f / liv[r];

  ushort* Po = (s == 0) ? Po0 : ((s == 1) ? Po1 : Po2);
  #pragma unroll
  for (int nt = 0; nt < 8; ++nt) {
    #pragma unroll
    for (int r = 0; r < 4; ++r) {
      const int n = n0q + wave*16 + quad*4 + r;
      Po[((size_t)h*N_ + n)*128 + nt*16 + m] = f2bf(Of[nt][r] * linv[r]);
    }
  }
  if (m == 0) {
    #pragma unroll
    for (int r = 0; r < 4; ++r) {
      const int n = n0q + wave*16 + quad*4 + r;
      Pml[(((size_t)s*8 + h)*N_ + n)*2 + 0] = mi[r];
      Pml[(((size_t)s*8 + h)*N_ + n)*2 + 1] = Of[8][r];
    }
  }
}

// ---------------- merge: combine 3 split-K partials (8 elems/thread) ------------
__global__ __launch_bounds__(256) void k_merge(
    const ushort* __restrict__ Po0, const ushort* __restrict__ Po1,
    const ushort* __restrict__ Po2, const float* __restrict__ Pml,
    ushort* __restrict__ out_v_b, ushort* __restrict__ out_g_b)
{
  const int idx = blockIdx.x*256 + threadIdx.x;
  const int c0 = (idx & 15) * 8;
  const int n  = (idx >> 4) & 4095;
  const int h  = idx >> 16;
  const float m1 = Pml[(((size_t)0*8 + h)*N_ + n)*2 + 0];
  const float l1 = Pml[(((size_t)0*8 + h)*N_ + n)*2 + 1];
  const float m2 = Pml[(((size_t)1*8 + h)*N_ + n)*2 + 0];
  const float l2 = Pml[(((size_t)1*8 + h)*N_ + n)*2 + 1];
  const float m3 = Pml[(((size_t)2*8 + h)*N_ + n)*2 + 0];
  const float l3 = Pml[(((size_t)2*8 + h)*N_ + n)*2 + 1];
  const float M = fmaxf(fmaxf(m1, m2), m3);
  const float w1 = exp2f(m1 - M) * l1;
  const float w2 = exp2f(m2 - M) * l2;
  const float w3 = exp2f(m3 - M) * l3;
  const float inv = 1.0f / (w1 + w2 + w3);
  union { short8 v; ushort u[8]; } a, b, c, res;
  a.v = *(const short8*)&Po0[((size_t)h*N_ + n)*128 + c0];
  b.v = *(const short8*)&Po1[((size_t)h*N_ + n)*128 + c0];
  c.v = *(const short8*)&Po2[((size_t)h*N_ + n)*128 + c0];
  #pragma unroll
  for (int j = 0; j < 8; ++j)
    res.u[j] = f2bf((w1*bf2f(a.u[j]) + w2*bf2f(b.u[j]) + w3*bf2f(c.u[j])) * inv);
  if (c0 < 32) {
    *(short8*)&out_v_b[(size_t)n*256 + h*32 + c0] = res.v;
  } else {
    const int j = (c0 - 32) >> 5, cc = (c0 - 32) & 31;
    *(short8*)&out_g_b[((size_t)n*3 + j)*256 + h*32 + cc] = res.v;
  }
}

// ---------------- k5a+k5b fused ----------------
__global__ __launch_bounds__(256) void k56ab(
    const ushort* __restrict__ out_v_b, const ushort* __restrict__ Wngt,
    const float* __restrict__ b_ng, const float* __restrict__ h,
    ushort* __restrict__ tmp_b,
    const ushort* __restrict__ out_g_b, const ushort* __restrict__ Wgoutt,
    const ushort* __restrict__ g_src_b, ushort* __restrict__ gsum_b)
{
  __shared__ __align__(16) ushort As[64*72], Bs[64*72];
  floatx4 acc[4];
  const int lane = threadIdx.x & 63, wave = threadIdx.x >> 6;
  const int quad = lane >> 4, m = lane & 15;
  const int bN = blockIdx.y*64;
  if (blockIdx.x < 64) {
    const int bM = blockIdx.x*64;
    gemm_core<256>(out_v_b, Wngt, bM, bN, acc, As, Bs);
    #pragma unroll
    for (int ct = 0; ct < 4; ++ct) {
      const int c = bN + ct*16 + m;
      #pragma unroll
      for (int r = 0; r < 4; ++r) {
        const int i = bM + wave*16 + quad*4 + r;
        tmp_b[(size_t)i*256 + c] =
            f2bf(acc[ct][r] + b_ng[c] + h[(size_t)i*256 + c] * SQRT_E);
      }
    }
  } else {
    const int bM = (blockIdx.x - 64)*64;
    gemm_core<256>(out_g_b, Wgoutt, bM, bN, acc, As, Bs);
    #pragma unroll
    for (int ct = 0; ct < 4; ++ct) {
      const int c = bN + ct*16 + m;
      #pragma unroll
      for (int r = 0; r < 4; ++r) {
        const int i = bM + wave*16 + quad*4 + r;
        gsum_b[(size_t)i*256 + c] =
            f2bf(acc[ct][r] + bf2f(g_src_b[(size_t)i*256 + c]));
      }
    }
  }
}

// ---------------- k5c+k5d fused ----------------
__global__ __launch_bounds__(256) void k56cd(
    const ushort* __restrict__ tmp_b, const ushort* __restrict__ Whdect,
    const float* __restrict__ b_hdec,
    const ushort* __restrict__ gsum_b, const ushort* __restrict__ Wgdect,
    float* __restrict__ out)
{
  __shared__ __align__(16) ushort As[64*72], Bs[64*72];
  const int t = threadIdx.x;
  const int lane = t & 63, wave = t >> 6;
  const int quad = lane >> 4, m = lane & 15;
  if (blockIdx.x < 64) {
    floatx4 acc[4];
    const int bM = blockIdx.x*64, bN = blockIdx.y*64;
    gemm_core<256>(tmp_b, Whdect, bM, bN, acc, As, Bs);
    #pragma unroll
    for (int ct = 0; ct < 4; ++ct) {
      const int c = bN + ct*16 + m;
      #pragma unroll
      for (int r = 0; r < 4; ++r) {
        const int i = bM + wave*16 + quad*4 + r;
        out[196608 + (size_t)i*256 + c] = acc[ct][r] + b_hdec[c];
      }
    }
  } else if (blockIdx.y == 0) {
    const int bM = (blockIdx.x - 64)*64;
    floatx4 acc = {0.f, 0.f, 0.f, 0.f};
    const int row = t >> 2, kq = (t & 3) * 8;
    for (int k0 = 0; k0 < 256; k0 += 32) {
      __syncthreads();
      *(short8*)&As[row*40 + kq] = *(const short8*)&gsum_b[(size_t)(bM+row)*256 + k0 + kq];
      if (t < 64)
        *(short8*)&Bs[(t>>2)*40 + kq] = *(const short8*)&Wgdect[(size_t)(t>>2)*256 + k0 + kq];
      __syncthreads();
      const short8 af = *(const short8*)&As[(wave*16 + m)*40 + quad*8];
      const short8 bf = *(const short8*)&Bs[m*40 + quad*8];
      acc = __builtin_amdgcn_mfma_f32_16x16x32_bf16(af, bf, acc, 0, 0, 0);
    }
    #pragma unroll
    for (int r = 0; r < 4; ++r)
      out[(size_t)(bM + wave*16 + quad*4 + r)*16 + m] = acc[r];
  }
}

extern "C" void kernel_launch(void* const* d_in, const int* in_sizes, int n_in,
                              void* d_out, int out_size, void* d_ws, size_t ws_size,
                              hipStream_t stream) {
  const float* equ    = (const float*)d_in[0];
  const float* h      = (const float*)d_in[1];
  const float* W_equ  = (const float*)d_in[4];
  const float* W_gproj= (const float*)d_in[5];
  const float* W_vg   = (const float*)d_in[6];
  const float* W_g1   = (const float*)d_in[7];
  const float* b_g1   = (const float*)d_in[8];
  const float* W_g2   = (const float*)d_in[9];
  const float* b_g2   = (const float*)d_in[10];
  const float* W_q    = (const float*)d_in[11];
  const float* b_q    = (const float*)d_in[12];
  const float* W_k    = (const float*)d_in[13];
  const float* b_k    = (const float*)d_in[14];
  const float* W_v    = (const float*)d_in[15];
  const float* b_v    = (const float*)d_in[16];
  const float* W_ng   = (const float*)d_in[17];
  const float* b_ng   = (const float*)d_in[18];
  const float* W_gout = (const float*)d_in[19];
  const float* W_gdec = (const float*)d_in[20];
  const float* W_hdec = (const float*)d_in[21];
  const float* b_hdec = (const float*)d_in[22];
  float* out = (float*)d_out;

  // ---- workspace layout (lifetimes annotated), peak 51.25 MiB (52 proven) ----
  char* wsb = (char*)d_ws;
  constexpr size_t MiB = 1048576;
  float*  q_ws    = (float*) (wsb +  0*MiB);            // 4 MiB [g34 -> k3]
  ushort* kh      = (ushort*)(wsb +  4*MiB);            // 2 MiB [g34 -> k3]
  ushort* vt      = (ushort*)(wsb +  8*MiB);            // 9 MiB [prep/g34 -> k3]
  ushort* h2h     = (ushort*)(wsb + 17*MiB);            // 4 MiB [prep/g2 -> g34]
  ushort* h2l     = (ushort*)(wsb + 21*MiB);            // 4 MiB
  ushort* g_src_b = (ushort*)(wsb + 25*MiB);            // 6 MiB [prep -> g34,k56ab]
  ushort* wbase   = (ushort*)(wsb + 31*MiB);            // 2.875 MiB [prep -> g34]
  ushort* Wg1t = wbase;                                 // 512x1024
  ushort* Wg2t = wbase + 524288;                        // 256x512
  ushort* Wth  = wbase + 655360;                        // 768x512 hi
  ushort* Wtl  = wbase + 1048576;                       // 768x512 lo
  ushort* Wvgt = wbase + 1441792;                       // 256x256
  ushort* wbase2  = (ushort*)(wsb + 34*MiB);            // 0.4 MiB [prep -> k56*]
  ushort* Wngt   = wbase2;                              // 256x256
  ushort* Wgoutt = wbase2 + 65536;                      // 256x256
  ushort* Whdect = wbase2 + 131072;                     // 256x256
  ushort* Wgdect = wbase2 + 196608;                     // 16x256
  ushort* gram_b  = (ushort*)(wsb + 34*MiB + 524288);   // 8 MiB [prep -> g1]
  ushort* hidden  = (ushort*)(wsb + 42*MiB + 524288);   // 4 MiB [g1 -> g2]
  // split-K x3 attention partials (all alias dead regions):
  ushort* Po0     = (ushort*)(wsb + 17*MiB);            // 8 MiB [k3 -> merge] alias h2h/h2l
  ushort* Po1     = (ushort*)(wsb + 34*MiB + 524288);   // 8 MiB [k3 -> merge] alias gram_b
  ushort* Po2     = (ushort*)(wsb + 42*MiB + 524288);   // 8 MiB [k3 -> merge] alias hidden+
  float*  Pml     = (float*) (wsb + 50*MiB + 524288);   // 0.75 MiB [k3 -> merge]
  ushort* out_v_b = (ushort*)(wsb +  4*MiB);            // 2 MiB [merge -> k56ab] alias kh
  ushort* out_g_b = (ushort*)(wsb +  8*MiB);            // 6 MiB [merge -> k56ab] alias vt
  ushort* tmp_b   = (ushort*)(wsb + 42*MiB + 524288);   // 2 MiB [k56ab -> k56cd] alias Po2
  ushort* gsum_b  = (ushort*)(wsb + 34*MiB + 524288);   // 6 MiB [k56ab -> k56cd] alias Po1

  // ---- 1 mega-prep launch (10 transposes + hsplit + vinit + k1) ----
  k_prep<<<11528, 256, 0, stream>>>(
      equ, h, W_equ, W_gproj, W_g1, W_g2, W_q, W_k, W_v,
      W_vg, W_ng, W_gout, W_hdec, W_gdec,
      Wg1t, Wg2t, Wth, Wtl, Wvgt, Wngt, Wgoutt, Whdect, Wgdect,
      h2h, h2l, vt, g_src_b, gram_b);

  // ---- GEMM chain (BK=64 double-pumped cores) ----
  k_g1<<<dim3(64, 8), 256, 0, stream>>>(gram_b, Wg1t, b_g1, hidden);
  k_g2<<<dim3(64, 4), 256, 0, stream>>>(hidden, Wg2t, b_g2, h2h, h2l);
  k_g34<<<dim3(192, 8), 256, 0, stream>>>(h2h, h2l, Wth, Wtl, b_q, b_k, b_v,
                                          g_src_b, Wvgt, q_ws, kh, vt);

  // ---- attention (TK=64, split-K x3, single-bf16 K, fast-exp2 P) + merge ----
  dim3 g3(64, 8, 3);
  k3_attn<<<g3, 256, 0, stream>>>(q_ws, kh, vt, Po0, Po1, Po2, Pml);
  k_merge<<<2048, 256, 0, stream>>>(Po0, Po1, Po2, Pml, out_v_b, out_g_b);

  // ---- epilogue GEMMs (fused pairs) ----
  k56ab<<<dim3(256, 4), 256, 0, stream>>>(out_v_b, Wngt, b_ng, h, tmp_b,
                                          out_g_b, Wgoutt, g_src_b, gsum_b);
  k56cd<<<dim3(256, 4), 256, 0, stream>>>(tmp_b, Whdect, b_hdec,
                                          gsum_b, Wgdect, out);
}